// Round 7
// baseline (1771.255 us; speedup 1.0000x reference)
//
#include <hip/hip_runtime.h>

typedef unsigned short u16;
typedef __attribute__((ext_vector_type(8))) __bf16 bf16x8;
typedef __attribute__((ext_vector_type(4))) float f32x4;

constexpr int C = 256;
constexpr int T = 4096;
constexpr int B = 4;
constexpr int NENC = 40;
constexpr int NDEC = 10;
constexpr int TILE = 64;

__device__ __forceinline__ float bf2f(u16 v) {
  union { unsigned u; float f; } x;
  x.u = ((unsigned)v) << 16;
  return x.f;
}
__device__ __forceinline__ u16 f2bf(float f) {
  union { float ff; unsigned u; } x;
  x.ff = f;
  unsigned r = x.u + 0x7fffu + ((x.u >> 16) & 1u);
  return (u16)(r >> 16);
}
// B1 LDS elem index; row stride 512 elems (1KB), 16B-granule XOR swizzle.
__device__ __forceinline__ int swz(int row, int col) {
  int g = ((row & 7) ^ (row >> 3)) & 7;
  return row * 512 + (col ^ (g << 3));
}

typedef __attribute__((address_space(1))) const unsigned int* gp1_t;
typedef __attribute__((address_space(3))) unsigned int* lp3_t;
__device__ __forceinline__ void gl_lds16(const u16* g, u16* l) {
  __builtin_amdgcn_global_load_lds((gp1_t)(const void*)g, (lp3_t)(void*)l, 16, 0, 0);
}

// merged bf16 conversion: [0,nFG)->Wf, [nFG,2nFG)->Wg, [2nFG,2nFG+nRS)->Wr
__global__ void k_cvtall(const float* __restrict__ Wf, const float* __restrict__ Wg,
                         const float* __restrict__ Wr,
                         u16* __restrict__ dWf, u16* __restrict__ dWg,
                         u16* __restrict__ dWr, int nFG, int nRS) {
  int i = blockIdx.x * 256 + threadIdx.x;
  if (i < nFG) dWf[i] = f2bf(Wf[i]);
  else if (i < 2 * nFG) dWg[i - nFG] = f2bf(Wg[i - nFG]);
  else if (i < 2 * nFG + nRS) dWr[i - 2 * nFG] = f2bf(Wr[i - 2 * nFG]);
}

__global__ void k_zero(float* __restrict__ p, int n) {
  int i = blockIdx.x * 256 + threadIdx.x;
  if (i < n) p[i] = 0.f;
}

// decoder weights -> bf16, [layer][co][ci]; f/g keep tap-1 only.
__global__ void k_tdec(const float* __restrict__ dWf, const float* __restrict__ dWg,
                       const float* __restrict__ dWr, const float* __restrict__ dinW,
                       u16* __restrict__ tWf, u16* __restrict__ tWg,
                       u16* __restrict__ tWr, u16* __restrict__ tdin) {
  int i = blockIdx.x * 256 + threadIdx.x;
  if (i < NDEC * C * C) {
    tWf[i] = f2bf(dWf[(size_t)i * 2 + 1]);
    tWg[i] = f2bf(dWg[(size_t)i * 2 + 1]);
    tWr[i] = f2bf(dWr[i]);
  }
  if (i < C * 128) tdin[i] = f2bf(dinW[i]);
}

__global__ void k_input(const float* __restrict__ x, const float* __restrict__ W,
                        const float* __restrict__ bin, float* __restrict__ h) {
  int idx = blockIdx.x * 256 + threadIdx.x;
  int t = idx & (T - 1);
  int c = (idx >> 12) & (C - 1);
  int b = idx >> 20;
  float xv = x[b * T + t];
  float xp = (t > 0) ? x[b * T + t - 1] : 0.f;
  h[idx] = W[2 * c] * xp + W[2 * c + 1] * xv + bin[c];
}

// Fused gated residual block. grid=256, block=512 (8 waves).
// Dynamic LDS 128KB: B1 64KB + wave-private weight double-buffer 64KB.
// Skip path: only row-sums of gated output accumulated (matvec done in k_skip).
__global__ __launch_bounds__(512, 2) void k_enc(
    const float* __restrict__ hin, float* __restrict__ hout, float* __restrict__ rowsum_l,
    const u16* __restrict__ Wf, const float* __restrict__ bfb,
    const u16* __restrict__ Wg, const float* __restrict__ bgb,
    const u16* __restrict__ Wr, const float* __restrict__ brb,
    int dil) {
  extern __shared__ __align__(16) u16 smem[];
  u16* wb = smem + 64 * 512;
  const int tid = threadIdx.x;
  const int wave = tid >> 6;
  const int lane = tid & 63;
  const int ncol = lane & 15;
  const int quad = lane >> 4;
  const int wg = blockIdx.x;
  const int b = wg >> 6;
  const int t0 = (wg & 63) * TILE;
  const float* hb = hin + b * C * T;

  const int co0 = wave * 32;
  const int kq = quad * 8;
  // DMA lane mapping: slot lane holds row lane&15, k-granule lane>>4.
  // Read side: lane (quad,ncol) wants row ncol, granule quad -> slot lane -> offset lane*8.
  const int lrow = lane & 15;
  const int lkg = (lane >> 4) * 8;
  const u16* pa0 = Wf + (co0 + lrow) * 512 + lkg;
  const u16* pa1 = Wf + (co0 + 16 + lrow) * 512 + lkg;
  const u16* pa2 = Wg + (co0 + lrow) * 512 + lkg;
  const u16* pa3 = Wg + (co0 + 16 + lrow) * 512 + lkg;
  u16* wreg0 = wb + wave * 2048;
  u16* wreg1 = wb + 16384 + wave * 2048;
  const int aoff = lane * 8;

  // ---- issue phase-1 chunks 0,1 ----
#pragma unroll
  for (int cc = 0; cc < 2; ++cc) {
    u16* ld = cc ? wreg1 : wreg0;
    gl_lds16(pa0 + cc * 32, ld);
    gl_lds16(pa1 + cc * 32, ld + 512);
    gl_lds16(pa2 + cc * 32, ld + 1024);
    gl_lds16(pa3 + cc * 32, ld + 1536);
  }

  // ---- stage B1: smem[n][2ci+tap] ----
  const int n4 = tid & 15;
  const int cib = tid >> 4;
  float4 v[16];
  const bool fast0 = ((dil & 3) == 0) && (t0 >= dil);
  if (fast0) {
#pragma unroll
    for (int it2 = 0; it2 < 16; ++it2) {
      int ci = (cib + it2 * 32) & 255;
      int tap = it2 >> 3;
      int tb = t0 + n4 * 4 - (tap ? 0 : dil);
      v[it2] = *(const float4*)(hb + ci * T + tb);
    }
  } else {
#pragma unroll
    for (int it2 = 0; it2 < 16; ++it2) {
      int ci = (cib + it2 * 32) & 255;
      int tap = it2 >> 3;
      int tb = t0 + n4 * 4 - (tap ? 0 : dil);
      const float* p = hb + ci * T + tb;
      if (tap) {
        v[it2] = *(const float4*)p;
      } else {
        v[it2].x = (tb + 0 >= 0) ? p[0] : 0.f;
        v[it2].y = (tb + 1 >= 0) ? p[1] : 0.f;
        v[it2].z = (tb + 2 >= 0) ? p[2] : 0.f;
        v[it2].w = (tb + 3 >= 0) ? p[3] : 0.f;
      }
    }
  }
#pragma unroll
  for (int it2 = 0; it2 < 8; ++it2) {
    int ci = (cib + it2 * 32) & 255;
    const float* p0 = (const float*)&v[it2];
    const float* p1 = (const float*)&v[it2 + 8];
#pragma unroll
    for (int r = 0; r < 4; ++r) {
      unsigned w32 = (unsigned)f2bf(p0[r]) | ((unsigned)f2bf(p1[r]) << 16);
      *(unsigned*)(&smem[swz(n4 * 4 + r, 2 * ci)]) = w32;
    }
  }
  __syncthreads();   // drains vmcnt(0): chunks 0,1 landed

  // ---- phase 1: [f;g] = W_fg @ B1, M=512 K=512 N=64 ----
  f32x4 acc[4][4];
#pragma unroll
  for (int m = 0; m < 4; ++m)
#pragma unroll
    for (int nt = 0; nt < 4; ++nt)
      acc[m][nt] = (f32x4){0.f, 0.f, 0.f, 0.f};

#pragma unroll
  for (int c = 0; c < 16; ++c) {
    if (c < 15) asm volatile("s_waitcnt vmcnt(4)" ::: "memory");
    else        asm volatile("s_waitcnt vmcnt(0)" ::: "memory");
    const u16* wr_ = (c & 1) ? wreg1 : wreg0;
    bf16x8 af0 = *(const bf16x8*)(wr_ + aoff);
    bf16x8 af1 = *(const bf16x8*)(wr_ + 512 + aoff);
    bf16x8 af2 = *(const bf16x8*)(wr_ + 1024 + aoff);
    bf16x8 af3 = *(const bf16x8*)(wr_ + 1536 + aoff);
    const int kk = c * 32 + kq;
    bf16x8 bfr[4];
#pragma unroll
    for (int nt = 0; nt < 4; ++nt)
      bfr[nt] = *(const bf16x8*)(&smem[swz(nt * 16 + ncol, kk)]);
#pragma unroll
    for (int nt = 0; nt < 4; ++nt) {
      acc[0][nt] = __builtin_amdgcn_mfma_f32_16x16x32_bf16(af0, bfr[nt], acc[0][nt], 0, 0, 0);
      acc[1][nt] = __builtin_amdgcn_mfma_f32_16x16x32_bf16(af1, bfr[nt], acc[1][nt], 0, 0, 0);
      acc[2][nt] = __builtin_amdgcn_mfma_f32_16x16x32_bf16(af2, bfr[nt], acc[2][nt], 0, 0, 0);
      acc[3][nt] = __builtin_amdgcn_mfma_f32_16x16x32_bf16(af3, bfr[nt], acc[3][nt], 0, 0, 0);
    }
    if (c + 2 < 16) {
      asm volatile("s_waitcnt lgkmcnt(0)" ::: "memory");
      u16* ld = (c & 1) ? wreg1 : wreg0;
      const int go = (c + 2) * 32;
      gl_lds16(pa0 + go, ld);
      gl_lds16(pa1 + go, ld + 512);
      gl_lds16(pa2 + go, ld + 1024);
      gl_lds16(pa3 + go, ld + 1536);
    }
  }

  // ---- issue phase-2 (res-only) chunks 0,1 ----
  const u16* pr0 = Wr + (co0 + lrow) * 256 + lkg;
  const u16* pr1 = Wr + (co0 + 16 + lrow) * 256 + lkg;
#pragma unroll
  for (int cc = 0; cc < 2; ++cc) {
    u16* ld = cc ? wreg1 : wreg0;
    gl_lds16(pr0 + cc * 32, ld);
    gl_lds16(pr1 + cc * 32, ld + 512);
  }
  __syncthreads();   // B1 reads done + p2 chunks 0,1 landed

  // ---- gating -> B2[k=co][n] in LDS, plus row-sum accumulation for skip ----
  float* rsb = rowsum_l + b * C;
#pragma unroll
  for (int j = 0; j < 2; ++j) {
    const int cob = co0 + j * 16 + quad * 4;
    float bfv[4], bgv[4], rs[4];
#pragma unroll
    for (int r = 0; r < 4; ++r) {
      bfv[r] = bfb[cob + r];
      bgv[r] = bgb[cob + r];
      rs[r] = 0.f;
    }
#pragma unroll
    for (int nt = 0; nt < 4; ++nt) {
      const int n = nt * 16 + ncol;
      u16 pk[4];
#pragma unroll
      for (int r = 0; r < 4; ++r) {
        float fv = acc[j][nt][r] + bfv[r];
        float gv = acc[2 + j][nt][r] + bgv[r];
        float th = 1.f - 2.f / (__expf(2.f * fv) + 1.f);
        float sg = 1.f / (1.f + __expf(-gv));
        float o = th * sg;
        rs[r] += o;
        pk[r] = f2bf(o);
      }
      uint2 w;
      w.x = (unsigned)pk[0] | ((unsigned)pk[1] << 16);
      w.y = (unsigned)pk[2] | ((unsigned)pk[3] << 16);
      *(uint2*)(&smem[swz(n, cob)]) = w;
    }
#pragma unroll
    for (int r = 0; r < 4; ++r) {
      float s = rs[r];
      s += __shfl_xor(s, 1);
      s += __shfl_xor(s, 2);
      s += __shfl_xor(s, 4);
      s += __shfl_xor(s, 8);
      if (ncol == 0) atomicAdd(&rsb[cob + r], s);
    }
  }
  __syncthreads();

  // ---- phase 2: res = Wr @ out, M=256 K=256 N=64 ----
  f32x4 acc2[2][4];
#pragma unroll
  for (int m = 0; m < 2; ++m)
#pragma unroll
    for (int nt = 0; nt < 4; ++nt)
      acc2[m][nt] = (f32x4){0.f, 0.f, 0.f, 0.f};

#pragma unroll
  for (int c = 0; c < 8; ++c) {
    if (c < 7) asm volatile("s_waitcnt vmcnt(2)" ::: "memory");
    else       asm volatile("s_waitcnt vmcnt(0)" ::: "memory");
    const u16* wr_ = (c & 1) ? wreg1 : wreg0;
    bf16x8 af0 = *(const bf16x8*)(wr_ + aoff);
    bf16x8 af1 = *(const bf16x8*)(wr_ + 512 + aoff);
    const int kk = c * 32 + kq;
    bf16x8 bfr[4];
#pragma unroll
    for (int nt = 0; nt < 4; ++nt)
      bfr[nt] = *(const bf16x8*)(&smem[swz(nt * 16 + ncol, kk)]);
#pragma unroll
    for (int nt = 0; nt < 4; ++nt) {
      acc2[0][nt] = __builtin_amdgcn_mfma_f32_16x16x32_bf16(af0, bfr[nt], acc2[0][nt], 0, 0, 0);
      acc2[1][nt] = __builtin_amdgcn_mfma_f32_16x16x32_bf16(af1, bfr[nt], acc2[1][nt], 0, 0, 0);
    }
    if (c + 2 < 8) {
      asm volatile("s_waitcnt lgkmcnt(0)" ::: "memory");
      u16* ld = (c & 1) ? wreg1 : wreg0;
      const int go = (c + 2) * 32;
      gl_lds16(pr0 + go, ld);
      gl_lds16(pr1 + go, ld + 512);
    }
  }

  // ---- epilogue: residual write (f32) ----
  float hold[32];
  float brv[2][4];
#pragma unroll
  for (int m = 0; m < 2; ++m)
#pragma unroll
    for (int r = 0; r < 4; ++r)
      brv[m][r] = brb[co0 + m * 16 + quad * 4 + r];
#pragma unroll
  for (int m = 0; m < 2; ++m)
#pragma unroll
    for (int nt = 0; nt < 4; ++nt)
#pragma unroll
      for (int r = 0; r < 4; ++r)
        hold[(m * 4 + nt) * 4 + r] =
            hb[(co0 + m * 16 + quad * 4 + r) * T + (t0 + nt * 16 + ncol)];

  float* ho = hout + b * C * T;
#pragma unroll
  for (int m = 0; m < 2; ++m)
#pragma unroll
    for (int nt = 0; nt < 4; ++nt)
#pragma unroll
      for (int r = 0; r < 4; ++r)
        ho[(co0 + m * 16 + quad * 4 + r) * T + (t0 + nt * 16 + ncol)] =
            acc2[m][nt][r] + brv[m][r] + hold[(m * 4 + nt) * 4 + r];
}

// per-layer skip matvec: pooled[b][co] += Ws_l[co,:] . rowsum[l][b,:] + T*bs_l[co]
__global__ __launch_bounds__(256) void k_skip(
    const float* __restrict__ encWs, const float* __restrict__ encbs,
    const float* __restrict__ rowsum, float* __restrict__ pooled) {
  __shared__ float rs[B][C];
  const int l = blockIdx.x;
  const int co = threadIdx.x;
  for (int i = co; i < B * C; i += 256) rs[i >> 8][i & 255] = rowsum[l * B * C + i];
  __syncthreads();
  const float* Wrow = encWs + (size_t)l * C * C + co * C;
  float bs = encbs[l * C + co] * (float)T;
  float d[B] = {0.f, 0.f, 0.f, 0.f};
  for (int ci = 0; ci < C; ci += 4) {
    float4 w = *(const float4*)(Wrow + ci);
#pragma unroll
    for (int b = 0; b < B; ++b)
      d[b] += w.x * rs[b][ci] + w.y * rs[b][ci + 1] + w.z * rs[b][ci + 2] + w.w * rs[b][ci + 3];
  }
#pragma unroll
  for (int b = 0; b < B; ++b) atomicAdd(&pooled[b * C + co], d[b] + bs);
}

// wave-per-dot FC
__global__ __launch_bounds__(256) void k_fc(
    const float* __restrict__ pooled,
    const float* __restrict__ muW, const float* __restrict__ mub,
    const float* __restrict__ lvW, const float* __restrict__ lvb,
    float* __restrict__ mlbuf, float* __restrict__ dout) {
  __shared__ float pm[B * C];
  const int tid = threadIdx.x;
  for (int i = tid; i < B * C; i += 256) pm[i] = pooled[i] * (1.f / (float)T);
  __syncthreads();
  const int waveG = blockIdx.x * 4 + (tid >> 6);
  const int lane = tid & 63;
  for (int j = 0; j < 16; ++j) {
    int d = waveG * 16 + j;
    int b = d >> 8, r = d & 255, which = r >> 7, l = r & 127;
    const float* Wrow = (which ? lvW : muW) + l * C;
    const float* p = pm + b * C;
    float s = Wrow[lane] * p[lane] + Wrow[lane + 64] * p[lane + 64] +
              Wrow[lane + 128] * p[lane + 128] + Wrow[lane + 192] * p[lane + 192];
#pragma unroll
    for (int off = 32; off; off >>= 1) s += __shfl_xor(s, off);
    if (lane == 0) {
      float val = s + (which ? lvb[l] : mub[l]);
      mlbuf[which * 512 + b * 128 + l] = val;
      dout[4 + which * 512 + b * 128 + l] = val;
    }
  }
}

// Decoder: 1 block, 16 waves, LDS-streamed weights (4-deep DMA pipeline).
__global__ __launch_bounds__(1024, 1) void k_dec(
    const float* __restrict__ mlbuf, const float* __restrict__ eps,
    const u16* __restrict__ tdin, const float* __restrict__ dinb,
    const u16* __restrict__ tWf, const float* __restrict__ dbf,
    const u16* __restrict__ tWg, const float* __restrict__ dbg,
    const u16* __restrict__ tWr, const float* __restrict__ dbr,
    const float* __restrict__ outW, const float* __restrict__ outb,
    float* __restrict__ dout) {
  extern __shared__ __align__(16) u16 dsm[];   // 16 waves x 4 bufs x 1024 elems = 128KB
  __shared__ __align__(16) u16 Ah[16][264];
  __shared__ __align__(16) u16 Ao[16][264];
  __shared__ float h2f[4][256];
  __shared__ float outred[4];
  const int tid = threadIdx.x;
  const int wave = tid >> 6;
  const int lane = tid & 63;
  const int ncol = lane & 15;
  const int quad = lane >> 4;
  const int kq = quad * 8;
  const int co = wave * 16 + ncol;
  const int co0 = wave * 16;
  const int lrow = lane & 15;
  const int lkg = (lane >> 4) * 8;
  u16* wreg = dsm + wave * 4096;   // 4 bufs x 1024 elems

  bf16x8 tdw[4];
  {
    const u16* wp = tdin + co * 128;
#pragma unroll
    for (int it = 0; it < 4; ++it) tdw[it] = *(const bf16x8*)(wp + it * 32 + kq);
  }

  if (tid < 512) {
    int b = tid >> 7, l = tid & 127;
    float mu = mlbuf[b * 128 + l];
    float lv = mlbuf[512 + b * 128 + l];
    Ah[b][l] = f2bf(mu + eps[b * 128 + l] * expf(0.5f * lv));
  }
  if (tid < 4) outred[tid] = 0.f;
  __syncthreads();

  // dec_in
  {
    f32x4 acch = (f32x4){0.f, 0.f, 0.f, 0.f};
#pragma unroll
    for (int it = 0; it < 4; ++it) {
      bf16x8 af = *(const bf16x8*)(&Ah[ncol][it * 32 + kq]);
      acch = __builtin_amdgcn_mfma_f32_16x16x32_bf16(af, tdw[it], acch, 0, 0, 0);
    }
    __syncthreads();
    if (quad == 0) {
      float bias = dinb[co];
#pragma unroll
      for (int r = 0; r < 4; ++r) {
        float hv = acch[r] + bias;
        h2f[r][co] = hv;
        Ah[r][co] = f2bf(hv);
      }
    }
  }
  // prefetch layer-0 f/g chunks 0..3 (drained by the barrier = landed)
  {
    const u16* wfp = tWf + (size_t)(co0 + lrow) * C + lkg;
    const u16* wgp = tWg + (size_t)(co0 + lrow) * C + lkg;
#pragma unroll
    for (int cc = 0; cc < 4; ++cc) {
      gl_lds16(wfp + cc * 32, wreg + cc * 1024);
      gl_lds16(wgp + cc * 32, wreg + cc * 1024 + 512);
    }
  }
  __syncthreads();

  for (int i = 0; i < NDEC; ++i) {
    const u16* wfp = tWf + (size_t)(i * C + co0 + lrow) * C + lkg;
    const u16* wgp = tWg + (size_t)(i * C + co0 + lrow) * C + lkg;
    const u16* wrp = tWr + (size_t)(i * C + co0 + lrow) * C + lkg;

    f32x4 accf = (f32x4){0.f, 0.f, 0.f, 0.f};
    f32x4 accg = (f32x4){0.f, 0.f, 0.f, 0.f};
#pragma unroll
    for (int c = 0; c < 8; ++c) {
      if (c == 4) asm volatile("s_waitcnt vmcnt(6)" ::: "memory");
      else if (c == 5) asm volatile("s_waitcnt vmcnt(4)" ::: "memory");
      else if (c == 6) asm volatile("s_waitcnt vmcnt(2)" ::: "memory");
      else if (c == 7) asm volatile("s_waitcnt vmcnt(0)" ::: "memory");
      const u16* bufp = wreg + (c & 3) * 1024;
      bf16x8 bf_ = *(const bf16x8*)(bufp + lane * 8);
      bf16x8 bg_ = *(const bf16x8*)(bufp + 512 + lane * 8);
      bf16x8 af = *(const bf16x8*)(&Ah[ncol][c * 32 + kq]);
      accf = __builtin_amdgcn_mfma_f32_16x16x32_bf16(af, bf_, accf, 0, 0, 0);
      accg = __builtin_amdgcn_mfma_f32_16x16x32_bf16(af, bg_, accg, 0, 0, 0);
      if (c < 4) {
        asm volatile("s_waitcnt lgkmcnt(0)" ::: "memory");
        gl_lds16(wfp + (c + 4) * 32, wreg + (c & 3) * 1024);
        gl_lds16(wgp + (c + 4) * 32, wreg + (c & 3) * 1024 + 512);
      }
    }
    asm volatile("s_waitcnt lgkmcnt(0)" ::: "memory");
#pragma unroll
    for (int cc = 0; cc < 4; ++cc) gl_lds16(wrp + cc * 32, wreg + cc * 1024);

    if (quad == 0) {
      float bfv = dbf[i * C + co];
      float bgv = dbg[i * C + co];
#pragma unroll
      for (int r = 0; r < 4; ++r) {
        float fv = accf[r] + bfv;
        float gv = accg[r] + bgv;
        float th = 1.f - 2.f / (__expf(2.f * fv) + 1.f);
        float sg = 1.f / (1.f + __expf(-gv));
        Ao[r][co] = f2bf(th * sg);
      }
    }
    __syncthreads();

    f32x4 accr = (f32x4){0.f, 0.f, 0.f, 0.f};
#pragma unroll
    for (int c = 0; c < 8; ++c) {
      if (c == 4) asm volatile("s_waitcnt vmcnt(3)" ::: "memory");
      else if (c == 5) asm volatile("s_waitcnt vmcnt(2)" ::: "memory");
      else if (c == 6) asm volatile("s_waitcnt vmcnt(1)" ::: "memory");
      else if (c == 7) asm volatile("s_waitcnt vmcnt(0)" ::: "memory");
      bf16x8 br_ = *(const bf16x8*)(wreg + (c & 3) * 1024 + lane * 8);
      bf16x8 af = *(const bf16x8*)(&Ao[ncol][c * 32 + kq]);
      accr = __builtin_amdgcn_mfma_f32_16x16x32_bf16(af, br_, accr, 0, 0, 0);
      if (c < 4) {
        asm volatile("s_waitcnt lgkmcnt(0)" ::: "memory");
        gl_lds16(wrp + (c + 4) * 32, wreg + (c & 3) * 1024);
      }
    }
    if (i + 1 < NDEC) {
      const u16* nwf = tWf + (size_t)((i + 1) * C + co0 + lrow) * C + lkg;
      const u16* nwg = tWg + (size_t)((i + 1) * C + co0 + lrow) * C + lkg;
      asm volatile("s_waitcnt lgkmcnt(0)" ::: "memory");
#pragma unroll
      for (int cc = 0; cc < 4; ++cc) {
        gl_lds16(nwf + cc * 32, wreg + cc * 1024);
        gl_lds16(nwg + cc * 32, wreg + cc * 1024 + 512);
      }
    }
    if (quad == 0) {
      float brv = dbr[i * C + co];
#pragma unroll
      for (int r = 0; r < 4; ++r) {
        float hv = h2f[r][co] + accr[r] + brv;
        h2f[r][co] = hv;
        Ah[r][co] = f2bf(hv);
      }
    }
    __syncthreads();
  }

  {
    int b = tid >> 8, c = tid & 255;
    float val = outW[c] * h2f[b][c];
#pragma unroll
    for (int off = 32; off; off >>= 1) val += __shfl_xor(val, off);
    if (lane == 0) atomicAdd(&outred[b], val);
  }
  __syncthreads();
  if (tid < 4) dout[tid] = outred[tid] + outb[0];
}

extern "C" void kernel_launch(void* const* d_in, const int* in_sizes, int n_in,
                              void* d_out, int out_size, void* d_ws, size_t ws_size,
                              hipStream_t stream) {
  const float* x      = (const float*)d_in[0];
  const float* eps    = (const float*)d_in[1];
  const float* encinW = (const float*)d_in[2];
  const float* encinb = (const float*)d_in[3];
  const float* encWf  = (const float*)d_in[4];
  const float* encbf  = (const float*)d_in[5];
  const float* encWg  = (const float*)d_in[6];
  const float* encbg  = (const float*)d_in[7];
  const float* encWr  = (const float*)d_in[8];
  const float* encbr  = (const float*)d_in[9];
  const float* encWs  = (const float*)d_in[10];
  const float* encbs  = (const float*)d_in[11];
  const float* muW    = (const float*)d_in[12];
  const float* mub    = (const float*)d_in[13];
  const float* lvW    = (const float*)d_in[14];
  const float* lvb    = (const float*)d_in[15];
  const float* dinW   = (const float*)d_in[16];
  const float* dinb   = (const float*)d_in[17];
  const float* dWf    = (const float*)d_in[18];
  const float* dbf    = (const float*)d_in[19];
  const float* dWg    = (const float*)d_in[20];
  const float* dbg    = (const float*)d_in[21];
  const float* dWr    = (const float*)d_in[22];
  const float* dbr    = (const float*)d_in[23];
  const float* outW   = (const float*)d_in[24];
  const float* outb   = (const float*)d_in[25];
  float* dout = (float*)d_out;

  const int nFG = NENC * C * C * 2;
  const int nRS = NENC * C * C;
  const int nTD = NDEC * C * C;

  char* ws = (char*)d_ws;
  float* hA = (float*)ws;
  float* hB = hA + (size_t)B * C * T;
  float* pooled = hB + (size_t)B * C * T;
  float* mlbuf = pooled + B * C;
  float* rowsum = mlbuf + 1024;                     // [40][4][256] f32
  u16* wWf = (u16*)(rowsum + NENC * B * C);
  u16* wWg = wWf + (size_t)nFG;
  u16* wWr = wWg + (size_t)nFG;
  u16* tWf = wWr + (size_t)nRS;
  u16* tWg = tWf + (size_t)nTD;
  u16* tWr = tWg + (size_t)nTD;
  u16* tdin = tWr + (size_t)nTD;

  (void)hipFuncSetAttribute(reinterpret_cast<const void*>(k_enc),
                            hipFuncAttributeMaxDynamicSharedMemorySize, 131072);
  (void)hipFuncSetAttribute(reinterpret_cast<const void*>(k_dec),
                            hipFuncAttributeMaxDynamicSharedMemorySize, 131072);

  const int nCvt = 2 * nFG + nRS;
  k_cvtall<<<(nCvt + 255) / 256, 256, 0, stream>>>(encWf, encWg, encWr, wWf, wWg, wWr, nFG, nRS);
  k_tdec<<<(nTD + 255) / 256, 256, 0, stream>>>(dWf, dWg, dWr, dinW, tWf, tWg, tWr, tdin);

  // zero pooled + mlbuf + rowsum (contiguous)
  const int nZ = B * C + 1024 + NENC * B * C;
  k_zero<<<(nZ + 255) / 256, 256, 0, stream>>>(pooled, nZ);
  k_input<<<(B * C * T) / 256, 256, 0, stream>>>(x, encinW, encinb, hA);

  for (int i = 0; i < NENC; ++i) {
    const int dil = 1 << (i % 10);
    const float* hi = (i & 1) ? hB : hA;
    float* ho = (i & 1) ? hA : hB;
    k_enc<<<256, 512, 131072, stream>>>(
        hi, ho, rowsum + (size_t)i * B * C,
        wWf + (size_t)i * C * C * 2, encbf + (size_t)i * C,
        wWg + (size_t)i * C * C * 2, encbg + (size_t)i * C,
        wWr + (size_t)i * C * C,     encbr + (size_t)i * C,
        dil);
  }

  k_skip<<<NENC, 256, 0, stream>>>(encWs, encbs, rowsum, pooled);
  k_fc<<<16, 256, 0, stream>>>(pooled, muW, mub, lvW, lvb, mlbuf, dout);
  k_dec<<<1, 1024, 131072, stream>>>(mlbuf, eps, tdin, dinb, tWf, dbf, tWg, dbg,
                                     tWr, dbr, outW, outb, dout);
}

// Round 8
// 1324.322 us; speedup vs baseline: 1.3375x; 1.3375x over previous
//
#include <hip/hip_runtime.h>

typedef unsigned short u16;
typedef __attribute__((ext_vector_type(8))) __bf16 bf16x8;
typedef __attribute__((ext_vector_type(4))) float f32x4;

constexpr int C = 256;
constexpr int T = 4096;
constexpr int B = 4;
constexpr int NENC = 40;
constexpr int NDEC = 10;
constexpr int TILE = 64;

__device__ __forceinline__ float bf2f(u16 v) {
  union { unsigned u; float f; } x;
  x.u = ((unsigned)v) << 16;
  return x.f;
}
__device__ __forceinline__ u16 f2bf(float f) {
  union { float ff; unsigned u; } x;
  x.ff = f;
  unsigned r = x.u + 0x7fffu + ((x.u >> 16) & 1u);
  return (u16)(r >> 16);
}
// B1 LDS elem index; row stride 512 elems (1KB), 16B-granule XOR swizzle.
__device__ __forceinline__ int swz(int row, int col) {
  int g = ((row & 7) ^ (row >> 3)) & 7;
  return row * 512 + (col ^ (g << 3));
}

typedef __attribute__((address_space(1))) const unsigned int* gp1_t;
typedef __attribute__((address_space(3))) unsigned int* lp3_t;
__device__ __forceinline__ void gl_lds16(const u16* g, u16* l) {
  __builtin_amdgcn_global_load_lds((gp1_t)(const void*)g, (lp3_t)(void*)l, 16, 0, 0);
}

// Pack encoder phase-1 weights (Wf,Wg) into DMA-contiguous chunks:
// penc1[((layer*8+wave)*16+c)*2048 + s*512 + lane*8 .. +8]
//   s=0: Wf rows co0..15, s=1: Wf rows 16..31, s=2/3: Wg same; lane=(kgran<<4)|row.
__global__ void k_pack1(const float* __restrict__ Wf, const float* __restrict__ Wg,
                        u16* __restrict__ penc1, int total) {
  int p = blockIdx.x * 256 + threadIdx.x;
  if (p >= total) return;
  int lane = p & 63;
  int s = (p >> 6) & 3;
  int c = (p >> 8) & 15;
  int wv = (p >> 12) & 7;
  int layer = p >> 15;
  int co = wv * 32 + (s & 1) * 16 + (lane & 15);
  int k = c * 32 + (lane >> 4) * 8;
  const float* src = (s >= 2 ? Wg : Wf) + ((size_t)layer * C + co) * 512 + k;
  u16* dst = penc1 + (size_t)p * 8;
#pragma unroll
  for (int r = 0; r < 8; ++r) dst[r] = f2bf(src[r]);
}

// Pack encoder phase-2 (Wr): penc2[((layer*8+wave)*8+c)*1024 + s*512 + lane*8]
__global__ void k_pack2(const float* __restrict__ Wr, u16* __restrict__ penc2, int total) {
  int p = blockIdx.x * 256 + threadIdx.x;
  if (p >= total) return;
  int lane = p & 63;
  int s = (p >> 6) & 1;
  int c = (p >> 7) & 7;
  int wv = (p >> 10) & 7;
  int layer = p >> 13;
  int co = wv * 32 + s * 16 + (lane & 15);
  int k = c * 32 + (lane >> 4) * 8;
  const float* src = Wr + ((size_t)layer * C + co) * 256 + k;
  u16* dst = penc2 + (size_t)p * 8;
#pragma unroll
  for (int r = 0; r < 8; ++r) dst[r] = f2bf(src[r]);
}

// Pack decoder weights (tap-1 of f/g convs, r 1x1) + tdin.
// fg: [0,163840): pdfg[((layer*16+wv)*8+c)*1024 + s*512 + lane*8]
// r : [163840,245760): pdr[((layer*16+wv)*8+c)*512 + lane*8]
// tdin: [245760,249856): tdin[u*8..]
__global__ void k_packd(const float* __restrict__ dWf, const float* __restrict__ dWg,
                        const float* __restrict__ dWr, const float* __restrict__ dinW,
                        u16* __restrict__ pdfg, u16* __restrict__ pdr,
                        u16* __restrict__ tdin) {
  int p = blockIdx.x * 256 + threadIdx.x;
  if (p < 163840) {
    int lane = p & 63;
    int s = (p >> 6) & 1;
    int c = (p >> 7) & 7;
    int wv = (p >> 10) & 15;
    int layer = p >> 14;
    int co = wv * 16 + (lane & 15);
    int k = c * 32 + (lane >> 4) * 8;
    const float* src = (s ? dWg : dWf) + (((size_t)(layer * C + co)) * C + k) * 2 + 1;
    u16* dst = pdfg + (size_t)p * 8;
#pragma unroll
    for (int r = 0; r < 8; ++r) dst[r] = f2bf(src[2 * r]);
  } else if (p < 245760) {
    int q = p - 163840;
    int lane = q & 63;
    int c = (q >> 6) & 7;
    int wv = (q >> 9) & 15;
    int layer = q >> 13;
    int co = wv * 16 + (lane & 15);
    int k = c * 32 + (lane >> 4) * 8;
    const float* src = dWr + ((size_t)(layer * C + co)) * C + k;
    u16* dst = pdr + (size_t)q * 8;
#pragma unroll
    for (int r = 0; r < 8; ++r) dst[r] = f2bf(src[r]);
  } else if (p < 249856) {
    int u = p - 245760;
#pragma unroll
    for (int r = 0; r < 8; ++r) tdin[u * 8 + r] = f2bf(dinW[u * 8 + r]);
  }
}

__global__ void k_zero(float* __restrict__ p, int n) {
  int i = blockIdx.x * 256 + threadIdx.x;
  if (i < n) p[i] = 0.f;
}

__global__ void k_input(const float* __restrict__ x, const float* __restrict__ W,
                        const float* __restrict__ bin, float* __restrict__ h) {
  int idx = blockIdx.x * 256 + threadIdx.x;
  int t = idx & (T - 1);
  int c = (idx >> 12) & (C - 1);
  int b = idx >> 20;
  float xv = x[b * T + t];
  float xp = (t > 0) ? x[b * T + t - 1] : 0.f;
  h[idx] = W[2 * c] * xp + W[2 * c + 1] * xv + bin[c];
}

// Fused gated residual block. grid=256, block=512 (8 waves).
// Dynamic LDS 128KB: B1 64KB + wave-private weight double-buffer 64KB.
// Weight stream sources are pre-packed contiguous 1KB-per-DMA blocks.
__global__ __launch_bounds__(512, 2) void k_enc(
    const float* __restrict__ hin, float* __restrict__ hout, float* __restrict__ rowsum_l,
    const u16* __restrict__ pw1, const float* __restrict__ bfb,
    const float* __restrict__ bgb,
    const u16* __restrict__ pw2, const float* __restrict__ brb,
    int dil) {
  extern __shared__ __align__(16) u16 smem[];
  u16* wb = smem + 64 * 512;
  const int tid = threadIdx.x;
  const int wave = tid >> 6;
  const int lane = tid & 63;
  const int ncol = lane & 15;
  const int quad = lane >> 4;
  const int wg = blockIdx.x;
  const int b = wg >> 6;
  const int t0 = (wg & 63) * TILE;
  const float* hb = hin + b * C * T;

  const int co0 = wave * 32;
  const int kq = quad * 8;
  const u16* b1 = pw1 + wave * 32768 + lane * 8;   // contiguous DMA source, phase 1
  const u16* b2 = pw2 + wave * 8192 + lane * 8;    // phase 2
  u16* wreg0 = wb + wave * 2048;
  u16* wreg1 = wb + 16384 + wave * 2048;
  const int aoff = lane * 8;

  // ---- issue phase-1 chunks 0,1 ----
#pragma unroll
  for (int cc = 0; cc < 2; ++cc) {
    u16* ld = cc ? wreg1 : wreg0;
    gl_lds16(b1 + cc * 2048, ld);
    gl_lds16(b1 + cc * 2048 + 512, ld + 512);
    gl_lds16(b1 + cc * 2048 + 1024, ld + 1024);
    gl_lds16(b1 + cc * 2048 + 1536, ld + 1536);
  }

  // ---- stage B1: smem[n][2ci+tap] ----
  const int n4 = tid & 15;
  const int cib = tid >> 4;
  float4 v[16];
  const bool fast0 = ((dil & 3) == 0) && (t0 >= dil);
  if (fast0) {
#pragma unroll
    for (int it2 = 0; it2 < 16; ++it2) {
      int ci = (cib + it2 * 32) & 255;
      int tap = it2 >> 3;
      int tb = t0 + n4 * 4 - (tap ? 0 : dil);
      v[it2] = *(const float4*)(hb + ci * T + tb);
    }
  } else {
#pragma unroll
    for (int it2 = 0; it2 < 16; ++it2) {
      int ci = (cib + it2 * 32) & 255;
      int tap = it2 >> 3;
      int tb = t0 + n4 * 4 - (tap ? 0 : dil);
      const float* p = hb + ci * T + tb;
      if (tap) {
        v[it2] = *(const float4*)p;
      } else {
        v[it2].x = (tb + 0 >= 0) ? p[0] : 0.f;
        v[it2].y = (tb + 1 >= 0) ? p[1] : 0.f;
        v[it2].z = (tb + 2 >= 0) ? p[2] : 0.f;
        v[it2].w = (tb + 3 >= 0) ? p[3] : 0.f;
      }
    }
  }
#pragma unroll
  for (int it2 = 0; it2 < 8; ++it2) {
    int ci = (cib + it2 * 32) & 255;
    const float* p0 = (const float*)&v[it2];
    const float* p1 = (const float*)&v[it2 + 8];
#pragma unroll
    for (int r = 0; r < 4; ++r) {
      unsigned w32 = (unsigned)f2bf(p0[r]) | ((unsigned)f2bf(p1[r]) << 16);
      *(unsigned*)(&smem[swz(n4 * 4 + r, 2 * ci)]) = w32;
    }
  }
  __syncthreads();   // drains vmcnt(0): chunks 0,1 landed

  // ---- phase 1: [f;g] = W_fg @ B1, M=512 K=512 N=64 ----
  f32x4 acc[4][4];
#pragma unroll
  for (int m = 0; m < 4; ++m)
#pragma unroll
    for (int nt = 0; nt < 4; ++nt)
      acc[m][nt] = (f32x4){0.f, 0.f, 0.f, 0.f};

#pragma unroll
  for (int c = 0; c < 16; ++c) {
    if (c < 15) asm volatile("s_waitcnt vmcnt(4)" ::: "memory");
    else        asm volatile("s_waitcnt vmcnt(0)" ::: "memory");
    const u16* wr_ = (c & 1) ? wreg1 : wreg0;
    bf16x8 af0 = *(const bf16x8*)(wr_ + aoff);
    bf16x8 af1 = *(const bf16x8*)(wr_ + 512 + aoff);
    bf16x8 af2 = *(const bf16x8*)(wr_ + 1024 + aoff);
    bf16x8 af3 = *(const bf16x8*)(wr_ + 1536 + aoff);
    const int kk = c * 32 + kq;
    bf16x8 bfr[4];
#pragma unroll
    for (int nt = 0; nt < 4; ++nt)
      bfr[nt] = *(const bf16x8*)(&smem[swz(nt * 16 + ncol, kk)]);
#pragma unroll
    for (int nt = 0; nt < 4; ++nt) {
      acc[0][nt] = __builtin_amdgcn_mfma_f32_16x16x32_bf16(af0, bfr[nt], acc[0][nt], 0, 0, 0);
      acc[1][nt] = __builtin_amdgcn_mfma_f32_16x16x32_bf16(af1, bfr[nt], acc[1][nt], 0, 0, 0);
      acc[2][nt] = __builtin_amdgcn_mfma_f32_16x16x32_bf16(af2, bfr[nt], acc[2][nt], 0, 0, 0);
      acc[3][nt] = __builtin_amdgcn_mfma_f32_16x16x32_bf16(af3, bfr[nt], acc[3][nt], 0, 0, 0);
    }
    if (c + 2 < 16) {
      asm volatile("s_waitcnt lgkmcnt(0)" ::: "memory");
      u16* ld = (c & 1) ? wreg1 : wreg0;
      const u16* gs = b1 + (c + 2) * 2048;
      gl_lds16(gs, ld);
      gl_lds16(gs + 512, ld + 512);
      gl_lds16(gs + 1024, ld + 1024);
      gl_lds16(gs + 1536, ld + 1536);
    }
  }

  // ---- issue phase-2 (res-only) chunks 0,1 ----
#pragma unroll
  for (int cc = 0; cc < 2; ++cc) {
    u16* ld = cc ? wreg1 : wreg0;
    gl_lds16(b2 + cc * 1024, ld);
    gl_lds16(b2 + cc * 1024 + 512, ld + 512);
  }
  __syncthreads();   // B1 reads done + p2 chunks 0,1 landed

  // ---- gating -> B2[k=co][n] in LDS, plus row-sum accumulation for skip ----
  float* rsb = rowsum_l + b * C;
#pragma unroll
  for (int j = 0; j < 2; ++j) {
    const int cob = co0 + j * 16 + quad * 4;
    float bfv[4], bgv[4], rs[4];
#pragma unroll
    for (int r = 0; r < 4; ++r) {
      bfv[r] = bfb[cob + r];
      bgv[r] = bgb[cob + r];
      rs[r] = 0.f;
    }
#pragma unroll
    for (int nt = 0; nt < 4; ++nt) {
      const int n = nt * 16 + ncol;
      u16 pk[4];
#pragma unroll
      for (int r = 0; r < 4; ++r) {
        float fv = acc[j][nt][r] + bfv[r];
        float gv = acc[2 + j][nt][r] + bgv[r];
        float th = 1.f - 2.f / (__expf(2.f * fv) + 1.f);
        float sg = 1.f / (1.f + __expf(-gv));
        float o = th * sg;
        rs[r] += o;
        pk[r] = f2bf(o);
      }
      uint2 w;
      w.x = (unsigned)pk[0] | ((unsigned)pk[1] << 16);
      w.y = (unsigned)pk[2] | ((unsigned)pk[3] << 16);
      *(uint2*)(&smem[swz(n, cob)]) = w;
    }
#pragma unroll
    for (int r = 0; r < 4; ++r) {
      float s = rs[r];
      s += __shfl_xor(s, 1);
      s += __shfl_xor(s, 2);
      s += __shfl_xor(s, 4);
      s += __shfl_xor(s, 8);
      if (ncol == 0) atomicAdd(&rsb[cob + r], s);
    }
  }
  __syncthreads();

  // ---- phase 2: res = Wr @ out, M=256 K=256 N=64 ----
  f32x4 acc2[2][4];
#pragma unroll
  for (int m = 0; m < 2; ++m)
#pragma unroll
    for (int nt = 0; nt < 4; ++nt)
      acc2[m][nt] = (f32x4){0.f, 0.f, 0.f, 0.f};

#pragma unroll
  for (int c = 0; c < 8; ++c) {
    if (c < 7) asm volatile("s_waitcnt vmcnt(2)" ::: "memory");
    else       asm volatile("s_waitcnt vmcnt(0)" ::: "memory");
    const u16* wr_ = (c & 1) ? wreg1 : wreg0;
    bf16x8 af0 = *(const bf16x8*)(wr_ + aoff);
    bf16x8 af1 = *(const bf16x8*)(wr_ + 512 + aoff);
    const int kk = c * 32 + kq;
    bf16x8 bfr[4];
#pragma unroll
    for (int nt = 0; nt < 4; ++nt)
      bfr[nt] = *(const bf16x8*)(&smem[swz(nt * 16 + ncol, kk)]);
#pragma unroll
    for (int nt = 0; nt < 4; ++nt) {
      acc2[0][nt] = __builtin_amdgcn_mfma_f32_16x16x32_bf16(af0, bfr[nt], acc2[0][nt], 0, 0, 0);
      acc2[1][nt] = __builtin_amdgcn_mfma_f32_16x16x32_bf16(af1, bfr[nt], acc2[1][nt], 0, 0, 0);
    }
    if (c + 2 < 8) {
      asm volatile("s_waitcnt lgkmcnt(0)" ::: "memory");
      u16* ld = (c & 1) ? wreg1 : wreg0;
      const u16* gs = b2 + (c + 2) * 1024;
      gl_lds16(gs, ld);
      gl_lds16(gs + 512, ld + 512);
    }
  }

  // ---- epilogue: residual write (f32) ----
  float hold[32];
  float brv[2][4];
#pragma unroll
  for (int m = 0; m < 2; ++m)
#pragma unroll
    for (int r = 0; r < 4; ++r)
      brv[m][r] = brb[co0 + m * 16 + quad * 4 + r];
#pragma unroll
  for (int m = 0; m < 2; ++m)
#pragma unroll
    for (int nt = 0; nt < 4; ++nt)
#pragma unroll
      for (int r = 0; r < 4; ++r)
        hold[(m * 4 + nt) * 4 + r] =
            hb[(co0 + m * 16 + quad * 4 + r) * T + (t0 + nt * 16 + ncol)];

  float* ho = hout + b * C * T;
#pragma unroll
  for (int m = 0; m < 2; ++m)
#pragma unroll
    for (int nt = 0; nt < 4; ++nt)
#pragma unroll
      for (int r = 0; r < 4; ++r)
        ho[(co0 + m * 16 + quad * 4 + r) * T + (t0 + nt * 16 + ncol)] =
            acc2[m][nt][r] + brv[m][r] + hold[(m * 4 + nt) * 4 + r];
}

// per-layer skip matvec: pooled[b][co] += Ws_l[co,:] . rowsum[l][b,:] + T*bs_l[co]
__global__ __launch_bounds__(256) void k_skip(
    const float* __restrict__ encWs, const float* __restrict__ encbs,
    const float* __restrict__ rowsum, float* __restrict__ pooled) {
  __shared__ float rs[B][C];
  const int l = blockIdx.x;
  const int co = threadIdx.x;
  for (int i = co; i < B * C; i += 256) rs[i >> 8][i & 255] = rowsum[l * B * C + i];
  __syncthreads();
  const float* Wrow = encWs + (size_t)l * C * C + co * C;
  float bs = encbs[l * C + co] * (float)T;
  float d[B] = {0.f, 0.f, 0.f, 0.f};
  for (int ci = 0; ci < C; ci += 4) {
    float4 w = *(const float4*)(Wrow + ci);
#pragma unroll
    for (int b = 0; b < B; ++b)
      d[b] += w.x * rs[b][ci] + w.y * rs[b][ci + 1] + w.z * rs[b][ci + 2] + w.w * rs[b][ci + 3];
  }
#pragma unroll
  for (int b = 0; b < B; ++b) atomicAdd(&pooled[b * C + co], d[b] + bs);
}

// wave-per-dot FC
__global__ __launch_bounds__(256) void k_fc(
    const float* __restrict__ pooled,
    const float* __restrict__ muW, const float* __restrict__ mub,
    const float* __restrict__ lvW, const float* __restrict__ lvb,
    float* __restrict__ mlbuf, float* __restrict__ dout) {
  __shared__ float pm[B * C];
  const int tid = threadIdx.x;
  for (int i = tid; i < B * C; i += 256) pm[i] = pooled[i] * (1.f / (float)T);
  __syncthreads();
  const int waveG = blockIdx.x * 4 + (tid >> 6);
  const int lane = tid & 63;
  for (int j = 0; j < 16; ++j) {
    int d = waveG * 16 + j;
    int b = d >> 8, r = d & 255, which = r >> 7, l = r & 127;
    const float* Wrow = (which ? lvW : muW) + l * C;
    const float* p = pm + b * C;
    float s = Wrow[lane] * p[lane] + Wrow[lane + 64] * p[lane + 64] +
              Wrow[lane + 128] * p[lane + 128] + Wrow[lane + 192] * p[lane + 192];
#pragma unroll
    for (int off = 32; off; off >>= 1) s += __shfl_xor(s, off);
    if (lane == 0) {
      float val = s + (which ? lvb[l] : mub[l]);
      mlbuf[which * 512 + b * 128 + l] = val;
      dout[4 + which * 512 + b * 128 + l] = val;
    }
  }
}

// Decoder: 1 block, 16 waves, contiguous-packed LDS-streamed weights.
__global__ __launch_bounds__(1024, 1) void k_dec(
    const float* __restrict__ mlbuf, const float* __restrict__ eps,
    const u16* __restrict__ tdin, const float* __restrict__ dinb,
    const u16* __restrict__ pdfg, const float* __restrict__ dbf,
    const float* __restrict__ dbg,
    const u16* __restrict__ pdr, const float* __restrict__ dbr,
    const float* __restrict__ outW, const float* __restrict__ outb,
    float* __restrict__ dout) {
  extern __shared__ __align__(16) u16 dsm[];   // 16 waves x 4 bufs x 1024 elems = 128KB
  __shared__ __align__(16) u16 Ah[16][264];
  __shared__ __align__(16) u16 Ao[16][264];
  __shared__ float h2f[4][256];
  __shared__ float outred[4];
  const int tid = threadIdx.x;
  const int wave = tid >> 6;
  const int lane = tid & 63;
  const int ncol = lane & 15;
  const int quad = lane >> 4;
  const int kq = quad * 8;
  const int co = wave * 16 + ncol;
  u16* wreg = dsm + wave * 4096;

  bf16x8 tdw[4];
  {
    const u16* wp = tdin + co * 128;
#pragma unroll
    for (int it = 0; it < 4; ++it) tdw[it] = *(const bf16x8*)(wp + it * 32 + kq);
  }

  if (tid < 512) {
    int b = tid >> 7, l = tid & 127;
    float mu = mlbuf[b * 128 + l];
    float lv = mlbuf[512 + b * 128 + l];
    Ah[b][l] = f2bf(mu + eps[b * 128 + l] * expf(0.5f * lv));
  }
  if (tid < 4) outred[tid] = 0.f;
  __syncthreads();

  // dec_in
  {
    f32x4 acch = (f32x4){0.f, 0.f, 0.f, 0.f};
#pragma unroll
    for (int it = 0; it < 4; ++it) {
      bf16x8 af = *(const bf16x8*)(&Ah[ncol][it * 32 + kq]);
      acch = __builtin_amdgcn_mfma_f32_16x16x32_bf16(af, tdw[it], acch, 0, 0, 0);
    }
    __syncthreads();
    if (quad == 0) {
      float bias = dinb[co];
#pragma unroll
      for (int r = 0; r < 4; ++r) {
        float hv = acch[r] + bias;
        h2f[r][co] = hv;
        Ah[r][co] = f2bf(hv);
      }
    }
  }
  // prefetch layer-0 f/g chunks 0..3
  {
    const u16* fb = pdfg + wave * 8192 + lane * 8;
#pragma unroll
    for (int cc = 0; cc < 4; ++cc) {
      gl_lds16(fb + cc * 1024, wreg + cc * 1024);
      gl_lds16(fb + cc * 1024 + 512, wreg + cc * 1024 + 512);
    }
  }
  __syncthreads();

  for (int i = 0; i < NDEC; ++i) {
    const u16* fb = pdfg + (i * 16 + wave) * 8192 + lane * 8;
    const u16* rb = pdr + (i * 16 + wave) * 4096 + lane * 8;

    f32x4 accf = (f32x4){0.f, 0.f, 0.f, 0.f};
    f32x4 accg = (f32x4){0.f, 0.f, 0.f, 0.f};
#pragma unroll
    for (int c = 0; c < 8; ++c) {
      if (c == 4) asm volatile("s_waitcnt vmcnt(6)" ::: "memory");
      else if (c == 5) asm volatile("s_waitcnt vmcnt(4)" ::: "memory");
      else if (c == 6) asm volatile("s_waitcnt vmcnt(2)" ::: "memory");
      else if (c == 7) asm volatile("s_waitcnt vmcnt(0)" ::: "memory");
      const u16* bufp = wreg + (c & 3) * 1024;
      bf16x8 bf_ = *(const bf16x8*)(bufp + lane * 8);
      bf16x8 bg_ = *(const bf16x8*)(bufp + 512 + lane * 8);
      bf16x8 af = *(const bf16x8*)(&Ah[ncol][c * 32 + kq]);
      accf = __builtin_amdgcn_mfma_f32_16x16x32_bf16(af, bf_, accf, 0, 0, 0);
      accg = __builtin_amdgcn_mfma_f32_16x16x32_bf16(af, bg_, accg, 0, 0, 0);
      if (c < 4) {
        asm volatile("s_waitcnt lgkmcnt(0)" ::: "memory");
        gl_lds16(fb + (c + 4) * 1024, wreg + (c & 3) * 1024);
        gl_lds16(fb + (c + 4) * 1024 + 512, wreg + (c & 3) * 1024 + 512);
      }
    }
    asm volatile("s_waitcnt lgkmcnt(0)" ::: "memory");
#pragma unroll
    for (int cc = 0; cc < 4; ++cc) gl_lds16(rb + cc * 512, wreg + cc * 1024);

    if (quad == 0) {
      float bfv = dbf[i * C + co];
      float bgv = dbg[i * C + co];
#pragma unroll
      for (int r = 0; r < 4; ++r) {
        float fv = accf[r] + bfv;
        float gv = accg[r] + bgv;
        float th = 1.f - 2.f / (__expf(2.f * fv) + 1.f);
        float sg = 1.f / (1.f + __expf(-gv));
        Ao[r][co] = f2bf(th * sg);
      }
    }
    __syncthreads();

    f32x4 accr = (f32x4){0.f, 0.f, 0.f, 0.f};
#pragma unroll
    for (int c = 0; c < 8; ++c) {
      if (c == 4) asm volatile("s_waitcnt vmcnt(3)" ::: "memory");
      else if (c == 5) asm volatile("s_waitcnt vmcnt(2)" ::: "memory");
      else if (c == 6) asm volatile("s_waitcnt vmcnt(1)" ::: "memory");
      else if (c == 7) asm volatile("s_waitcnt vmcnt(0)" ::: "memory");
      bf16x8 br_ = *(const bf16x8*)(wreg + (c & 3) * 1024 + lane * 8);
      bf16x8 af = *(const bf16x8*)(&Ao[ncol][c * 32 + kq]);
      accr = __builtin_amdgcn_mfma_f32_16x16x32_bf16(af, br_, accr, 0, 0, 0);
      if (c < 4) {
        asm volatile("s_waitcnt lgkmcnt(0)" ::: "memory");
        gl_lds16(rb + (c + 4) * 512, wreg + (c & 3) * 1024);
      }
    }
    if (i + 1 < NDEC) {
      const u16* nfb = pdfg + ((i + 1) * 16 + wave) * 8192 + lane * 8;
      asm volatile("s_waitcnt lgkmcnt(0)" ::: "memory");
#pragma unroll
      for (int cc = 0; cc < 4; ++cc) {
        gl_lds16(nfb + cc * 1024, wreg + cc * 1024);
        gl_lds16(nfb + cc * 1024 + 512, wreg + cc * 1024 + 512);
      }
    }
    if (quad == 0) {
      float brv = dbr[i * C + co];
#pragma unroll
      for (int r = 0; r < 4; ++r) {
        float hv = h2f[r][co] + accr[r] + brv;
        h2f[r][co] = hv;
        Ah[r][co] = f2bf(hv);
      }
    }
    __syncthreads();
  }

  {
    int b = tid >> 8, c = tid & 255;
    float val = outW[c] * h2f[b][c];
#pragma unroll
    for (int off = 32; off; off >>= 1) val += __shfl_xor(val, off);
    if (lane == 0) atomicAdd(&outred[b], val);
  }
  __syncthreads();
  if (tid < 4) dout[tid] = outred[tid] + outb[0];
}

extern "C" void kernel_launch(void* const* d_in, const int* in_sizes, int n_in,
                              void* d_out, int out_size, void* d_ws, size_t ws_size,
                              hipStream_t stream) {
  const float* x      = (const float*)d_in[0];
  const float* eps    = (const float*)d_in[1];
  const float* encinW = (const float*)d_in[2];
  const float* encinb = (const float*)d_in[3];
  const float* encWf  = (const float*)d_in[4];
  const float* encbf  = (const float*)d_in[5];
  const float* encWg  = (const float*)d_in[6];
  const float* encbg  = (const float*)d_in[7];
  const float* encWr  = (const float*)d_in[8];
  const float* encbr  = (const float*)d_in[9];
  const float* encWs  = (const float*)d_in[10];
  const float* encbs  = (const float*)d_in[11];
  const float* muW    = (const float*)d_in[12];
  const float* mub    = (const float*)d_in[13];
  const float* lvW    = (const float*)d_in[14];
  const float* lvb    = (const float*)d_in[15];
  const float* dinW   = (const float*)d_in[16];
  const float* dinb   = (const float*)d_in[17];
  const float* dWf    = (const float*)d_in[18];
  const float* dbf    = (const float*)d_in[19];
  const float* dWg    = (const float*)d_in[20];
  const float* dbg    = (const float*)d_in[21];
  const float* dWr    = (const float*)d_in[22];
  const float* dbr    = (const float*)d_in[23];
  const float* outW   = (const float*)d_in[24];
  const float* outb   = (const float*)d_in[25];
  float* dout = (float*)d_out;

  char* ws = (char*)d_ws;
  float* hA = (float*)ws;
  float* hB = hA + (size_t)B * C * T;
  float* pooled = hB + (size_t)B * C * T;
  float* mlbuf = pooled + B * C;
  float* rowsum = mlbuf + 1024;                     // [40][4][256] f32
  u16* penc1 = (u16*)(rowsum + NENC * B * C);       // 10,485,760
  u16* penc2 = penc1 + (size_t)10485760;            // 2,621,440
  u16* pdfg = penc2 + (size_t)2621440;              // 1,310,720
  u16* pdr = pdfg + (size_t)1310720;                // 655,360
  u16* tdin = pdr + (size_t)655360;                 // 32,768

  (void)hipFuncSetAttribute(reinterpret_cast<const void*>(k_enc),
                            hipFuncAttributeMaxDynamicSharedMemorySize, 131072);
  (void)hipFuncSetAttribute(reinterpret_cast<const void*>(k_dec),
                            hipFuncAttributeMaxDynamicSharedMemorySize, 131072);

  k_pack1<<<(1310720 + 255) / 256, 256, 0, stream>>>(encWf, encWg, penc1, 1310720);
  k_pack2<<<(327680 + 255) / 256, 256, 0, stream>>>(encWr, penc2, 327680);
  k_packd<<<(249856 + 255) / 256, 256, 0, stream>>>(dWf, dWg, dWr, dinW, pdfg, pdr, tdin);

  const int nZ = B * C + 1024 + NENC * B * C;
  k_zero<<<(nZ + 255) / 256, 256, 0, stream>>>(pooled, nZ);
  k_input<<<(B * C * T) / 256, 256, 0, stream>>>(x, encinW, encinb, hA);

  for (int i = 0; i < NENC; ++i) {
    const int dil = 1 << (i % 10);
    const float* hi = (i & 1) ? hB : hA;
    float* ho = (i & 1) ? hA : hB;
    k_enc<<<256, 512, 131072, stream>>>(
        hi, ho, rowsum + (size_t)i * B * C,
        penc1 + (size_t)i * 262144, encbf + (size_t)i * C,
        encbg + (size_t)i * C,
        penc2 + (size_t)i * 65536, encbr + (size_t)i * C,
        dil);
  }

  k_skip<<<NENC, 256, 0, stream>>>(encWs, encbs, rowsum, pooled);
  k_fc<<<16, 256, 0, stream>>>(pooled, muW, mub, lvW, lvb, mlbuf, dout);
  k_dec<<<1, 1024, 131072, stream>>>(mlbuf, eps, tdin, dinb, pdfg, dbf, dbg,
                                     pdr, dbr, outW, outb, dout);
}

// Round 9
// 1279.081 us; speedup vs baseline: 1.3848x; 1.0354x over previous
//
#include <hip/hip_runtime.h>

typedef unsigned short u16;
typedef __attribute__((ext_vector_type(8))) __bf16 bf16x8;
typedef __attribute__((ext_vector_type(4))) float f32x4;

constexpr int C = 256;
constexpr int T = 4096;
constexpr int B = 4;
constexpr int NENC = 40;
constexpr int NDEC = 10;
constexpr int TILE = 64;

__device__ __forceinline__ float bf2f(u16 v) {
  union { unsigned u; float f; } x;
  x.u = ((unsigned)v) << 16;
  return x.f;
}
__device__ __forceinline__ u16 f2bf(float f) {
  union { float ff; unsigned u; } x;
  x.ff = f;
  unsigned r = x.u + 0x7fffu + ((x.u >> 16) & 1u);
  return (u16)(r >> 16);
}
// B1 LDS elem index; row stride 512 elems (1KB), 16B-granule XOR swizzle.
__device__ __forceinline__ int swz(int row, int col) {
  int g = ((row & 7) ^ (row >> 3)) & 7;
  return row * 512 + (col ^ (g << 3));
}

typedef __attribute__((address_space(1))) const unsigned int* gp1_t;
typedef __attribute__((address_space(3))) unsigned int* lp3_t;
__device__ __forceinline__ void gl_lds16(const u16* g, u16* l) {
  __builtin_amdgcn_global_load_lds((gp1_t)(const void*)g, (lp3_t)(void*)l, 16, 0, 0);
}

// Pack encoder phase-1 weights (Wf,Wg) into DMA-contiguous chunks:
// penc1[((layer*8+wave)*16+c)*2048 + s*512 + lane*8]; lane=(kgran<<4)|row.
__global__ void k_pack1(const float* __restrict__ Wf, const float* __restrict__ Wg,
                        u16* __restrict__ penc1, int total) {
  int p = blockIdx.x * 256 + threadIdx.x;
  if (p >= total) return;
  int lane = p & 63;
  int s = (p >> 6) & 3;
  int c = (p >> 8) & 15;
  int wv = (p >> 12) & 7;
  int layer = p >> 15;
  int co = wv * 32 + (s & 1) * 16 + (lane & 15);
  int k = c * 32 + (lane >> 4) * 8;
  const float* src = (s >= 2 ? Wg : Wf) + ((size_t)layer * C + co) * 512 + k;
  u16* dst = penc1 + (size_t)p * 8;
#pragma unroll
  for (int r = 0; r < 8; ++r) dst[r] = f2bf(src[r]);
}

// Pack encoder phase-2 (Wr): penc2[((layer*8+wave)*8+c)*1024 + s*512 + lane*8]
__global__ void k_pack2(const float* __restrict__ Wr, u16* __restrict__ penc2, int total) {
  int p = blockIdx.x * 256 + threadIdx.x;
  if (p >= total) return;
  int lane = p & 63;
  int s = (p >> 6) & 1;
  int c = (p >> 7) & 7;
  int wv = (p >> 10) & 7;
  int layer = p >> 13;
  int co = wv * 32 + s * 16 + (lane & 15);
  int k = c * 32 + (lane >> 4) * 8;
  const float* src = Wr + ((size_t)layer * C + co) * 256 + k;
  u16* dst = penc2 + (size_t)p * 8;
#pragma unroll
  for (int r = 0; r < 8; ++r) dst[r] = f2bf(src[r]);
}

// Pack decoder weights (tap-1 of f/g convs, r 1x1) + tdin.
__global__ void k_packd(const float* __restrict__ dWf, const float* __restrict__ dWg,
                        const float* __restrict__ dWr, const float* __restrict__ dinW,
                        u16* __restrict__ pdfg, u16* __restrict__ pdr,
                        u16* __restrict__ tdin) {
  int p = blockIdx.x * 256 + threadIdx.x;
  if (p < 163840) {
    int lane = p & 63;
    int s = (p >> 6) & 1;
    int c = (p >> 7) & 7;
    int wv = (p >> 10) & 15;
    int layer = p >> 14;
    int co = wv * 16 + (lane & 15);
    int k = c * 32 + (lane >> 4) * 8;
    const float* src = (s ? dWg : dWf) + (((size_t)(layer * C + co)) * C + k) * 2 + 1;
    u16* dst = pdfg + (size_t)p * 8;
#pragma unroll
    for (int r = 0; r < 8; ++r) dst[r] = f2bf(src[2 * r]);
  } else if (p < 245760) {
    int q = p - 163840;
    int lane = q & 63;
    int c = (q >> 6) & 7;
    int wv = (q >> 9) & 15;
    int layer = q >> 13;
    int co = wv * 16 + (lane & 15);
    int k = c * 32 + (lane >> 4) * 8;
    const float* src = dWr + ((size_t)(layer * C + co)) * C + k;
    u16* dst = pdr + (size_t)q * 8;
#pragma unroll
    for (int r = 0; r < 8; ++r) dst[r] = f2bf(src[r]);
  } else if (p < 249856) {
    int u = p - 245760;
#pragma unroll
    for (int r = 0; r < 8; ++r) tdin[u * 8 + r] = f2bf(dinW[u * 8 + r]);
  }
}

__global__ void k_zero(float* __restrict__ p, int n) {
  int i = blockIdx.x * 256 + threadIdx.x;
  if (i < n) p[i] = 0.f;
}

__global__ void k_input(const float* __restrict__ x, const float* __restrict__ W,
                        const float* __restrict__ bin, float* __restrict__ h) {
  int idx = blockIdx.x * 256 + threadIdx.x;
  int t = idx & (T - 1);
  int c = (idx >> 12) & (C - 1);
  int b = idx >> 20;
  float xv = x[b * T + t];
  float xp = (t > 0) ? x[b * T + t - 1] : 0.f;
  h[idx] = W[2 * c] * xp + W[2 * c + 1] * xv + bin[c];
}

// Fused gated residual block. grid=256, block=512 (8 waves).
// Dynamic LDS 128KB: B1 64KB + wave-private weight double-buffer 64KB.
// Epilogue: acc2+br transposed through LDS (f32, stride 66) -> float4 stores;
// residual h comes from the tap-1 staging registers (no global re-read).
__global__ __launch_bounds__(512, 2) void k_enc(
    const float* __restrict__ hin, float* __restrict__ hout, float* __restrict__ rowsum_l,
    const u16* __restrict__ pw1, const float* __restrict__ bfb,
    const float* __restrict__ bgb,
    const u16* __restrict__ pw2, const float* __restrict__ brb,
    int dil) {
  extern __shared__ __align__(16) u16 smem[];
  u16* wb = smem + 64 * 512;
  const int tid = threadIdx.x;
  const int wave = tid >> 6;
  const int lane = tid & 63;
  const int ncol = lane & 15;
  const int quad = lane >> 4;
  const int wg = blockIdx.x;
  const int b = wg >> 6;
  const int t0 = (wg & 63) * TILE;
  const float* hb = hin + b * C * T;

  const int co0 = wave * 32;
  const int kq = quad * 8;
  const u16* b1 = pw1 + wave * 32768 + lane * 8;   // contiguous DMA source, phase 1
  const u16* b2 = pw2 + wave * 8192 + lane * 8;    // phase 2
  u16* wreg0 = wb + wave * 2048;
  u16* wreg1 = wb + 16384 + wave * 2048;
  const int aoff = lane * 8;

  // ---- issue phase-1 chunks 0,1 ----
#pragma unroll
  for (int cc = 0; cc < 2; ++cc) {
    u16* ld = cc ? wreg1 : wreg0;
    gl_lds16(b1 + cc * 2048, ld);
    gl_lds16(b1 + cc * 2048 + 512, ld + 512);
    gl_lds16(b1 + cc * 2048 + 1024, ld + 1024);
    gl_lds16(b1 + cc * 2048 + 1536, ld + 1536);
  }

  // ---- stage B1: smem[n][2ci+tap] ----
  const int n4 = tid & 15;
  const int cib = tid >> 4;
  float4 v[16];
  const bool al4 = ((dil & 3) == 0);
  if (t0 >= dil) {
    // all addresses in-bounds; tap-1 always 16B-aligned, tap-0 component loads if unaligned
#pragma unroll
    for (int it2 = 0; it2 < 16; ++it2) {
      int ci = (cib + it2 * 32) & 255;
      int tap = it2 >> 3;
      int tb = t0 + n4 * 4 - (tap ? 0 : dil);
      const float* p = hb + ci * T + tb;
      if (tap || al4) {
        v[it2] = *(const float4*)p;
      } else {
        v[it2].x = p[0]; v[it2].y = p[1]; v[it2].z = p[2]; v[it2].w = p[3];
      }
    }
  } else {
#pragma unroll
    for (int it2 = 0; it2 < 16; ++it2) {
      int ci = (cib + it2 * 32) & 255;
      int tap = it2 >> 3;
      int tb = t0 + n4 * 4 - (tap ? 0 : dil);
      const float* p = hb + ci * T + tb;
      if (tap) {
        v[it2] = *(const float4*)p;
      } else {
        v[it2].x = (tb + 0 >= 0) ? p[0] : 0.f;
        v[it2].y = (tb + 1 >= 0) ? p[1] : 0.f;
        v[it2].z = (tb + 2 >= 0) ? p[2] : 0.f;
        v[it2].w = (tb + 3 >= 0) ? p[3] : 0.f;
      }
    }
  }
#pragma unroll
  for (int it2 = 0; it2 < 8; ++it2) {
    int ci = (cib + it2 * 32) & 255;
    const float* p0 = (const float*)&v[it2];
    const float* p1 = (const float*)&v[it2 + 8];
#pragma unroll
    for (int r = 0; r < 4; ++r) {
      unsigned w32 = (unsigned)f2bf(p0[r]) | ((unsigned)f2bf(p1[r]) << 16);
      *(unsigned*)(&smem[swz(n4 * 4 + r, 2 * ci)]) = w32;
    }
  }
  __syncthreads();   // drains vmcnt(0): chunks 0,1 landed

  // ---- phase 1: [f;g] = W_fg @ B1, M=512 K=512 N=64 ----
  f32x4 acc[4][4];
#pragma unroll
  for (int m = 0; m < 4; ++m)
#pragma unroll
    for (int nt = 0; nt < 4; ++nt)
      acc[m][nt] = (f32x4){0.f, 0.f, 0.f, 0.f};

#pragma unroll
  for (int c = 0; c < 16; ++c) {
    if (c < 15) asm volatile("s_waitcnt vmcnt(4)" ::: "memory");
    else        asm volatile("s_waitcnt vmcnt(0)" ::: "memory");
    const u16* wr_ = (c & 1) ? wreg1 : wreg0;
    bf16x8 af0 = *(const bf16x8*)(wr_ + aoff);
    bf16x8 af1 = *(const bf16x8*)(wr_ + 512 + aoff);
    bf16x8 af2 = *(const bf16x8*)(wr_ + 1024 + aoff);
    bf16x8 af3 = *(const bf16x8*)(wr_ + 1536 + aoff);
    const int kk = c * 32 + kq;
    bf16x8 bfr[4];
#pragma unroll
    for (int nt = 0; nt < 4; ++nt)
      bfr[nt] = *(const bf16x8*)(&smem[swz(nt * 16 + ncol, kk)]);
#pragma unroll
    for (int nt = 0; nt < 4; ++nt) {
      acc[0][nt] = __builtin_amdgcn_mfma_f32_16x16x32_bf16(af0, bfr[nt], acc[0][nt], 0, 0, 0);
      acc[1][nt] = __builtin_amdgcn_mfma_f32_16x16x32_bf16(af1, bfr[nt], acc[1][nt], 0, 0, 0);
      acc[2][nt] = __builtin_amdgcn_mfma_f32_16x16x32_bf16(af2, bfr[nt], acc[2][nt], 0, 0, 0);
      acc[3][nt] = __builtin_amdgcn_mfma_f32_16x16x32_bf16(af3, bfr[nt], acc[3][nt], 0, 0, 0);
    }
    if (c + 2 < 16) {
      asm volatile("s_waitcnt lgkmcnt(0)" ::: "memory");
      u16* ld = (c & 1) ? wreg1 : wreg0;
      const u16* gs = b1 + (c + 2) * 2048;
      gl_lds16(gs, ld);
      gl_lds16(gs + 512, ld + 512);
      gl_lds16(gs + 1024, ld + 1024);
      gl_lds16(gs + 1536, ld + 1536);
    }
  }

  // ---- issue phase-2 (res-only) chunks 0,1 ----
#pragma unroll
  for (int cc = 0; cc < 2; ++cc) {
    u16* ld = cc ? wreg1 : wreg0;
    gl_lds16(b2 + cc * 1024, ld);
    gl_lds16(b2 + cc * 1024 + 512, ld + 512);
  }
  __syncthreads();   // B1 reads done + p2 chunks 0,1 landed

  // ---- gating -> B2[k=co][n] in LDS, plus row-sum accumulation for skip ----
  float* rsb = rowsum_l + b * C;
#pragma unroll
  for (int j = 0; j < 2; ++j) {
    const int cob = co0 + j * 16 + quad * 4;
    float bfv[4], bgv[4], rs[4];
#pragma unroll
    for (int r = 0; r < 4; ++r) {
      bfv[r] = bfb[cob + r];
      bgv[r] = bgb[cob + r];
      rs[r] = 0.f;
    }
#pragma unroll
    for (int nt = 0; nt < 4; ++nt) {
      const int n = nt * 16 + ncol;
      u16 pk[4];
#pragma unroll
      for (int r = 0; r < 4; ++r) {
        float fv = acc[j][nt][r] + bfv[r];
        float gv = acc[2 + j][nt][r] + bgv[r];
        float th = 1.f - 2.f / (__expf(2.f * fv) + 1.f);
        float sg = 1.f / (1.f + __expf(-gv));
        float o = th * sg;
        rs[r] += o;
        pk[r] = f2bf(o);
      }
      uint2 w;
      w.x = (unsigned)pk[0] | ((unsigned)pk[1] << 16);
      w.y = (unsigned)pk[2] | ((unsigned)pk[3] << 16);
      *(uint2*)(&smem[swz(n, cob)]) = w;
    }
#pragma unroll
    for (int r = 0; r < 4; ++r) {
      float s = rs[r];
      s += __shfl_xor(s, 1);
      s += __shfl_xor(s, 2);
      s += __shfl_xor(s, 4);
      s += __shfl_xor(s, 8);
      if (ncol == 0) atomicAdd(&rsb[cob + r], s);
    }
  }
  __syncthreads();

  // ---- phase 2: res = Wr @ out, M=256 K=256 N=64 ----
  f32x4 acc2[2][4];
#pragma unroll
  for (int m = 0; m < 2; ++m)
#pragma unroll
    for (int nt = 0; nt < 4; ++nt)
      acc2[m][nt] = (f32x4){0.f, 0.f, 0.f, 0.f};

#pragma unroll
  for (int c = 0; c < 8; ++c) {
    if (c < 7) asm volatile("s_waitcnt vmcnt(2)" ::: "memory");
    else       asm volatile("s_waitcnt vmcnt(0)" ::: "memory");
    const u16* wr_ = (c & 1) ? wreg1 : wreg0;
    bf16x8 af0 = *(const bf16x8*)(wr_ + aoff);
    bf16x8 af1 = *(const bf16x8*)(wr_ + 512 + aoff);
    const int kk = c * 32 + kq;
    bf16x8 bfr[4];
#pragma unroll
    for (int nt = 0; nt < 4; ++nt)
      bfr[nt] = *(const bf16x8*)(&smem[swz(nt * 16 + ncol, kk)]);
#pragma unroll
    for (int nt = 0; nt < 4; ++nt) {
      acc2[0][nt] = __builtin_amdgcn_mfma_f32_16x16x32_bf16(af0, bfr[nt], acc2[0][nt], 0, 0, 0);
      acc2[1][nt] = __builtin_amdgcn_mfma_f32_16x16x32_bf16(af1, bfr[nt], acc2[1][nt], 0, 0, 0);
    }
    if (c + 2 < 8) {
      asm volatile("s_waitcnt lgkmcnt(0)" ::: "memory");
      u16* ld = (c & 1) ? wreg1 : wreg0;
      const u16* gs = b2 + (c + 2) * 1024;
      gl_lds16(gs, ld);
      gl_lds16(gs + 512, ld + 512);
    }
  }
  __syncthreads();   // all waves done reading B2; LDS free for transpose

  // ---- epilogue: transpose res through LDS (f32, stride 66), float4 stores ----
  float* fb = (float*)smem;   // [256][66] f32 = 67.6 KB (fits in 128 KB dynamic)
#pragma unroll
  for (int m = 0; m < 2; ++m) {
    const int cob = co0 + m * 16 + quad * 4;
#pragma unroll
    for (int nt = 0; nt < 4; ++nt) {
      const int t = nt * 16 + ncol;
#pragma unroll
      for (int r = 0; r < 4; ++r)
        fb[(cob + r) * 66 + t] = acc2[m][nt][r] + brb[cob + r];
    }
  }
  __syncthreads();
  float* ho = hout + b * C * T;
#pragma unroll
  for (int it2 = 0; it2 < 8; ++it2) {
    const int ci = cib + it2 * 32;
    const float* fr = fb + ci * 66 + n4 * 4;
    float4 o;
    o.x = fr[0] + v[it2 + 8].x;
    o.y = fr[1] + v[it2 + 8].y;
    o.z = fr[2] + v[it2 + 8].z;
    o.w = fr[3] + v[it2 + 8].w;
    *(float4*)(ho + ci * T + t0 + n4 * 4) = o;
  }
}

// per-layer skip matvec: pooled[b][co] += Ws_l[co,:] . rowsum[l][b,:] + T*bs_l[co]
__global__ __launch_bounds__(256) void k_skip(
    const float* __restrict__ encWs, const float* __restrict__ encbs,
    const float* __restrict__ rowsum, float* __restrict__ pooled) {
  __shared__ float rs[B][C];
  const int l = blockIdx.x;
  const int co = threadIdx.x;
  for (int i = co; i < B * C; i += 256) rs[i >> 8][i & 255] = rowsum[l * B * C + i];
  __syncthreads();
  const float* Wrow = encWs + (size_t)l * C * C + co * C;
  float bs = encbs[l * C + co] * (float)T;
  float d[B] = {0.f, 0.f, 0.f, 0.f};
  for (int ci = 0; ci < C; ci += 4) {
    float4 w = *(const float4*)(Wrow + ci);
#pragma unroll
    for (int b = 0; b < B; ++b)
      d[b] += w.x * rs[b][ci] + w.y * rs[b][ci + 1] + w.z * rs[b][ci + 2] + w.w * rs[b][ci + 3];
  }
#pragma unroll
  for (int b = 0; b < B; ++b) atomicAdd(&pooled[b * C + co], d[b] + bs);
}

// wave-per-dot FC
__global__ __launch_bounds__(256) void k_fc(
    const float* __restrict__ pooled,
    const float* __restrict__ muW, const float* __restrict__ mub,
    const float* __restrict__ lvW, const float* __restrict__ lvb,
    float* __restrict__ mlbuf, float* __restrict__ dout) {
  __shared__ float pm[B * C];
  const int tid = threadIdx.x;
  for (int i = tid; i < B * C; i += 256) pm[i] = pooled[i] * (1.f / (float)T);
  __syncthreads();
  const int waveG = blockIdx.x * 4 + (tid >> 6);
  const int lane = tid & 63;
  for (int j = 0; j < 16; ++j) {
    int d = waveG * 16 + j;
    int b = d >> 8, r = d & 255, which = r >> 7, l = r & 127;
    const float* Wrow = (which ? lvW : muW) + l * C;
    const float* p = pm + b * C;
    float s = Wrow[lane] * p[lane] + Wrow[lane + 64] * p[lane + 64] +
              Wrow[lane + 128] * p[lane + 128] + Wrow[lane + 192] * p[lane + 192];
#pragma unroll
    for (int off = 32; off; off >>= 1) s += __shfl_xor(s, off);
    if (lane == 0) {
      float val = s + (which ? lvb[l] : mub[l]);
      mlbuf[which * 512 + b * 128 + l] = val;
      dout[4 + which * 512 + b * 128 + l] = val;
    }
  }
}

// Decoder: 1 block, 16 waves, contiguous-packed LDS-streamed weights.
__global__ __launch_bounds__(1024, 1) void k_dec(
    const float* __restrict__ mlbuf, const float* __restrict__ eps,
    const u16* __restrict__ tdin, const float* __restrict__ dinb,
    const u16* __restrict__ pdfg, const float* __restrict__ dbf,
    const float* __restrict__ dbg,
    const u16* __restrict__ pdr, const float* __restrict__ dbr,
    const float* __restrict__ outW, const float* __restrict__ outb,
    float* __restrict__ dout) {
  extern __shared__ __align__(16) u16 dsm[];   // 16 waves x 4 bufs x 1024 elems = 128KB
  __shared__ __align__(16) u16 Ah[16][264];
  __shared__ __align__(16) u16 Ao[16][264];
  __shared__ float h2f[4][256];
  __shared__ float outred[4];
  const int tid = threadIdx.x;
  const int wave = tid >> 6;
  const int lane = tid & 63;
  const int ncol = lane & 15;
  const int quad = lane >> 4;
  const int kq = quad * 8;
  const int co = wave * 16 + ncol;
  u16* wreg = dsm + wave * 4096;

  bf16x8 tdw[4];
  {
    const u16* wp = tdin + co * 128;
#pragma unroll
    for (int it = 0; it < 4; ++it) tdw[it] = *(const bf16x8*)(wp + it * 32 + kq);
  }

  if (tid < 512) {
    int b = tid >> 7, l = tid & 127;
    float mu = mlbuf[b * 128 + l];
    float lv = mlbuf[512 + b * 128 + l];
    Ah[b][l] = f2bf(mu + eps[b * 128 + l] * expf(0.5f * lv));
  }
  if (tid < 4) outred[tid] = 0.f;
  __syncthreads();

  // dec_in
  {
    f32x4 acch = (f32x4){0.f, 0.f, 0.f, 0.f};
#pragma unroll
    for (int it = 0; it < 4; ++it) {
      bf16x8 af = *(const bf16x8*)(&Ah[ncol][it * 32 + kq]);
      acch = __builtin_amdgcn_mfma_f32_16x16x32_bf16(af, tdw[it], acch, 0, 0, 0);
    }
    __syncthreads();
    if (quad == 0) {
      float bias = dinb[co];
#pragma unroll
      for (int r = 0; r < 4; ++r) {
        float hv = acch[r] + bias;
        h2f[r][co] = hv;
        Ah[r][co] = f2bf(hv);
      }
    }
  }
  // prefetch layer-0 f/g chunks 0..3
  {
    const u16* fb = pdfg + wave * 8192 + lane * 8;
#pragma unroll
    for (int cc = 0; cc < 4; ++cc) {
      gl_lds16(fb + cc * 1024, wreg + cc * 1024);
      gl_lds16(fb + cc * 1024 + 512, wreg + cc * 1024 + 512);
    }
  }
  __syncthreads();

  for (int i = 0; i < NDEC; ++i) {
    const u16* fb = pdfg + (i * 16 + wave) * 8192 + lane * 8;
    const u16* rb = pdr + (i * 16 + wave) * 4096 + lane * 8;

    f32x4 accf = (f32x4){0.f, 0.f, 0.f, 0.f};
    f32x4 accg = (f32x4){0.f, 0.f, 0.f, 0.f};
#pragma unroll
    for (int c = 0; c < 8; ++c) {
      if (c == 4) asm volatile("s_waitcnt vmcnt(6)" ::: "memory");
      else if (c == 5) asm volatile("s_waitcnt vmcnt(4)" ::: "memory");
      else if (c == 6) asm volatile("s_waitcnt vmcnt(2)" ::: "memory");
      else if (c == 7) asm volatile("s_waitcnt vmcnt(0)" ::: "memory");
      const u16* bufp = wreg + (c & 3) * 1024;
      bf16x8 bf_ = *(const bf16x8*)(bufp + lane * 8);
      bf16x8 bg_ = *(const bf16x8*)(bufp + 512 + lane * 8);
      bf16x8 af = *(const bf16x8*)(&Ah[ncol][c * 32 + kq]);
      accf = __builtin_amdgcn_mfma_f32_16x16x32_bf16(af, bf_, accf, 0, 0, 0);
      accg = __builtin_amdgcn_mfma_f32_16x16x32_bf16(af, bg_, accg, 0, 0, 0);
      if (c < 4) {
        asm volatile("s_waitcnt lgkmcnt(0)" ::: "memory");
        gl_lds16(fb + (c + 4) * 1024, wreg + (c & 3) * 1024);
        gl_lds16(fb + (c + 4) * 1024 + 512, wreg + (c & 3) * 1024 + 512);
      }
    }
    asm volatile("s_waitcnt lgkmcnt(0)" ::: "memory");
#pragma unroll
    for (int cc = 0; cc < 4; ++cc) gl_lds16(rb + cc * 512, wreg + cc * 1024);

    if (quad == 0) {
      float bfv = dbf[i * C + co];
      float bgv = dbg[i * C + co];
#pragma unroll
      for (int r = 0; r < 4; ++r) {
        float fv = accf[r] + bfv;
        float gv = accg[r] + bgv;
        float th = 1.f - 2.f / (__expf(2.f * fv) + 1.f);
        float sg = 1.f / (1.f + __expf(-gv));
        Ao[r][co] = f2bf(th * sg);
      }
    }
    __syncthreads();

    f32x4 accr = (f32x4){0.f, 0.f, 0.f, 0.f};
#pragma unroll
    for (int c = 0; c < 8; ++c) {
      if (c == 4) asm volatile("s_waitcnt vmcnt(3)" ::: "memory");
      else if (c == 5) asm volatile("s_waitcnt vmcnt(2)" ::: "memory");
      else if (c == 6) asm volatile("s_waitcnt vmcnt(1)" ::: "memory");
      else if (c == 7) asm volatile("s_waitcnt vmcnt(0)" ::: "memory");
      bf16x8 br_ = *(const bf16x8*)(wreg + (c & 3) * 1024 + lane * 8);
      bf16x8 af = *(const bf16x8*)(&Ao[ncol][c * 32 + kq]);
      accr = __builtin_amdgcn_mfma_f32_16x16x32_bf16(af, br_, accr, 0, 0, 0);
      if (c < 4) {
        asm volatile("s_waitcnt lgkmcnt(0)" ::: "memory");
        gl_lds16(rb + (c + 4) * 512, wreg + (c & 3) * 1024);
      }
    }
    if (i + 1 < NDEC) {
      const u16* nfb = pdfg + ((i + 1) * 16 + wave) * 8192 + lane * 8;
      asm volatile("s_waitcnt lgkmcnt(0)" ::: "memory");
#pragma unroll
      for (int cc = 0; cc < 4; ++cc) {
        gl_lds16(nfb + cc * 1024, wreg + cc * 1024);
        gl_lds16(nfb + cc * 1024 + 512, wreg + cc * 1024 + 512);
      }
    }
    if (quad == 0) {
      float brv = dbr[i * C + co];
#pragma unroll
      for (int r = 0; r < 4; ++r) {
        float hv = h2f[r][co] + accr[r] + brv;
        h2f[r][co] = hv;
        Ah[r][co] = f2bf(hv);
      }
    }
    __syncthreads();
  }

  {
    int b = tid >> 8, c = tid & 255;
    float val = outW[c] * h2f[b][c];
#pragma unroll
    for (int off = 32; off; off >>= 1) val += __shfl_xor(val, off);
    if (lane == 0) atomicAdd(&outred[b], val);
  }
  __syncthreads();
  if (tid < 4) dout[tid] = outred[tid] + outb[0];
}

extern "C" void kernel_launch(void* const* d_in, const int* in_sizes, int n_in,
                              void* d_out, int out_size, void* d_ws, size_t ws_size,
                              hipStream_t stream) {
  const float* x      = (const float*)d_in[0];
  const float* eps    = (const float*)d_in[1];
  const float* encinW = (const float*)d_in[2];
  const float* encinb = (const float*)d_in[3];
  const float* encWf  = (const float*)d_in[4];
  const float* encbf  = (const float*)d_in[5];
  const float* encWg  = (const float*)d_in[6];
  const float* encbg  = (const float*)d_in[7];
  const float* encWr  = (const float*)d_in[8];
  const float* encbr  = (const float*)d_in[9];
  const float* encWs  = (const float*)d_in[10];
  const float* encbs  = (const float*)d_in[11];
  const float* muW    = (const float*)d_in[12];
  const float* mub    = (const float*)d_in[13];
  const float* lvW    = (const float*)d_in[14];
  const float* lvb    = (const float*)d_in[15];
  const float* dinW   = (const float*)d_in[16];
  const float* dinb   = (const float*)d_in[17];
  const float* dWf    = (const float*)d_in[18];
  const float* dbf    = (const float*)d_in[19];
  const float* dWg    = (const float*)d_in[20];
  const float* dbg    = (const float*)d_in[21];
  const float* dWr    = (const float*)d_in[22];
  const float* dbr    = (const float*)d_in[23];
  const float* outW   = (const float*)d_in[24];
  const float* outb   = (const float*)d_in[25];
  float* dout = (float*)d_out;

  char* ws = (char*)d_ws;
  float* hA = (float*)ws;
  float* hB = hA + (size_t)B * C * T;
  float* pooled = hB + (size_t)B * C * T;
  float* mlbuf = pooled + B * C;
  float* rowsum = mlbuf + 1024;                     // [40][4][256] f32
  u16* penc1 = (u16*)(rowsum + NENC * B * C);       // 10,485,760
  u16* penc2 = penc1 + (size_t)10485760;            // 2,621,440
  u16* pdfg = penc2 + (size_t)2621440;              // 1,310,720
  u16* pdr = pdfg + (size_t)1310720;                // 655,360
  u16* tdin = pdr + (size_t)655360;                 // 32,768

  (void)hipFuncSetAttribute(reinterpret_cast<const void*>(k_enc),
                            hipFuncAttributeMaxDynamicSharedMemorySize, 131072);
  (void)hipFuncSetAttribute(reinterpret_cast<const void*>(k_dec),
                            hipFuncAttributeMaxDynamicSharedMemorySize, 131072);

  k_pack1<<<(1310720 + 255) / 256, 256, 0, stream>>>(encWf, encWg, penc1, 1310720);
  k_pack2<<<(327680 + 255) / 256, 256, 0, stream>>>(encWr, penc2, 327680);
  k_packd<<<(249856 + 255) / 256, 256, 0, stream>>>(dWf, dWg, dWr, dinW, pdfg, pdr, tdin);

  const int nZ = B * C + 1024 + NENC * B * C;
  k_zero<<<(nZ + 255) / 256, 256, 0, stream>>>(pooled, nZ);
  k_input<<<(B * C * T) / 256, 256, 0, stream>>>(x, encinW, encinb, hA);

  for (int i = 0; i < NENC; ++i) {
    const int dil = 1 << (i % 10);
    const float* hi = (i & 1) ? hB : hA;
    float* ho = (i & 1) ? hA : hB;
    k_enc<<<256, 512, 131072, stream>>>(
        hi, ho, rowsum + (size_t)i * B * C,
        penc1 + (size_t)i * 262144, encbf + (size_t)i * C,
        encbg + (size_t)i * C,
        penc2 + (size_t)i * 65536, encbr + (size_t)i * C,
        dil);
  }

  k_skip<<<NENC, 256, 0, stream>>>(encWs, encbs, rowsum, pooled);
  k_fc<<<16, 256, 0, stream>>>(pooled, muW, mub, lvW, lvb, mlbuf, dout);
  k_dec<<<1, 1024, 131072, stream>>>(mlbuf, eps, tdin, dinb, pdfg, dbf, dbg,
                                     pdr, dbr, outW, outb, dout);
}

// Round 10
// 1270.384 us; speedup vs baseline: 1.3943x; 1.0068x over previous
//
#include <hip/hip_runtime.h>

typedef unsigned short u16;
typedef __attribute__((ext_vector_type(8))) __bf16 bf16x8;
typedef __attribute__((ext_vector_type(4))) float f32x4;

constexpr int C = 256;
constexpr int T = 4096;
constexpr int B = 4;
constexpr int NENC = 40;
constexpr int NDEC = 10;
constexpr int TILE = 64;

__device__ __forceinline__ float bf2f(u16 v) {
  union { unsigned u; float f; } x;
  x.u = ((unsigned)v) << 16;
  return x.f;
}
__device__ __forceinline__ u16 f2bf(float f) {
  union { float ff; unsigned u; } x;
  x.ff = f;
  unsigned r = x.u + 0x7fffu + ((x.u >> 16) & 1u);
  return (u16)(r >> 16);
}
// B1 LDS elem index; row stride 512 elems (1KB), 16B-granule XOR swizzle.
__device__ __forceinline__ int swz(int row, int col) {
  int g = ((row & 7) ^ (row >> 3)) & 7;
  return row * 512 + (col ^ (g << 3));
}

typedef __attribute__((address_space(1))) const unsigned int* gp1_t;
typedef __attribute__((address_space(3))) unsigned int* lp3_t;
__device__ __forceinline__ void gl_lds16(const u16* g, u16* l) {
  __builtin_amdgcn_global_load_lds((gp1_t)(const void*)g, (lp3_t)(void*)l, 16, 0, 0);
}

// Pack encoder phase-1 weights (Wf,Wg) into DMA-contiguous chunks:
// penc1[((layer*8+wave)*16+c)*2048 + s*512 + lane*8]; lane=(kgran<<4)|row.
__global__ void k_pack1(const float* __restrict__ Wf, const float* __restrict__ Wg,
                        u16* __restrict__ penc1, int total) {
  int p = blockIdx.x * 256 + threadIdx.x;
  if (p >= total) return;
  int lane = p & 63;
  int s = (p >> 6) & 3;
  int c = (p >> 8) & 15;
  int wv = (p >> 12) & 7;
  int layer = p >> 15;
  int co = wv * 32 + (s & 1) * 16 + (lane & 15);
  int k = c * 32 + (lane >> 4) * 8;
  const float* src = (s >= 2 ? Wg : Wf) + ((size_t)layer * C + co) * 512 + k;
  u16* dst = penc1 + (size_t)p * 8;
#pragma unroll
  for (int r = 0; r < 8; ++r) dst[r] = f2bf(src[r]);
}

// Pack encoder phase-2 (Wr): penc2[((layer*8+wave)*8+c)*1024 + s*512 + lane*8]
__global__ void k_pack2(const float* __restrict__ Wr, u16* __restrict__ penc2, int total) {
  int p = blockIdx.x * 256 + threadIdx.x;
  if (p >= total) return;
  int lane = p & 63;
  int s = (p >> 6) & 1;
  int c = (p >> 7) & 7;
  int wv = (p >> 10) & 7;
  int layer = p >> 13;
  int co = wv * 32 + s * 16 + (lane & 15);
  int k = c * 32 + (lane >> 4) * 8;
  const float* src = Wr + ((size_t)layer * C + co) * 256 + k;
  u16* dst = penc2 + (size_t)p * 8;
#pragma unroll
  for (int r = 0; r < 8; ++r) dst[r] = f2bf(src[r]);
}

// Pack decoder weights (tap-1 of f/g convs, r 1x1) + tdin.
__global__ void k_packd(const float* __restrict__ dWf, const float* __restrict__ dWg,
                        const float* __restrict__ dWr, const float* __restrict__ dinW,
                        u16* __restrict__ pdfg, u16* __restrict__ pdr,
                        u16* __restrict__ tdin) {
  int p = blockIdx.x * 256 + threadIdx.x;
  if (p < 163840) {
    int lane = p & 63;
    int s = (p >> 6) & 1;
    int c = (p >> 7) & 7;
    int wv = (p >> 10) & 15;
    int layer = p >> 14;
    int co = wv * 16 + (lane & 15);
    int k = c * 32 + (lane >> 4) * 8;
    const float* src = (s ? dWg : dWf) + (((size_t)(layer * C + co)) * C + k) * 2 + 1;
    u16* dst = pdfg + (size_t)p * 8;
#pragma unroll
    for (int r = 0; r < 8; ++r) dst[r] = f2bf(src[2 * r]);
  } else if (p < 245760) {
    int q = p - 163840;
    int lane = q & 63;
    int c = (q >> 6) & 7;
    int wv = (q >> 9) & 15;
    int layer = q >> 13;
    int co = wv * 16 + (lane & 15);
    int k = c * 32 + (lane >> 4) * 8;
    const float* src = dWr + ((size_t)(layer * C + co)) * C + k;
    u16* dst = pdr + (size_t)q * 8;
#pragma unroll
    for (int r = 0; r < 8; ++r) dst[r] = f2bf(src[r]);
  } else if (p < 249856) {
    int u = p - 245760;
#pragma unroll
    for (int r = 0; r < 8; ++r) tdin[u * 8 + r] = f2bf(dinW[u * 8 + r]);
  }
}

__global__ void k_zero(float* __restrict__ p, int n) {
  int i = blockIdx.x * 256 + threadIdx.x;
  if (i < n) p[i] = 0.f;
}

__global__ void k_input(const float* __restrict__ x, const float* __restrict__ W,
                        const float* __restrict__ bin, float* __restrict__ h) {
  int idx = blockIdx.x * 256 + threadIdx.x;
  int t = idx & (T - 1);
  int c = (idx >> 12) & (C - 1);
  int b = idx >> 20;
  float xv = x[b * T + t];
  float xp = (t > 0) ? x[b * T + t - 1] : 0.f;
  h[idx] = W[2 * c] * xp + W[2 * c + 1] * xv + bin[c];
}

// Fused gated residual block. grid=256, block=512 (8 waves).
// Weight K-chunk order is staggered per XCD-local block index so the 32 CUs
// of an XCD hit different L2 banks instead of serializing on one address.
__global__ __launch_bounds__(512, 2) void k_enc(
    const float* __restrict__ hin, float* __restrict__ hout, float* __restrict__ rowsum_l,
    const u16* __restrict__ pw1, const float* __restrict__ bfb,
    const float* __restrict__ bgb,
    const u16* __restrict__ pw2, const float* __restrict__ brb,
    int dil) {
  extern __shared__ __align__(16) u16 smem[];
  u16* wb = smem + 64 * 512;
  const int tid = threadIdx.x;
  const int wave = tid >> 6;
  const int lane = tid & 63;
  const int ncol = lane & 15;
  const int quad = lane >> 4;
  const int wg = blockIdx.x;
  const int b = wg >> 6;
  const int t0 = (wg & 63) * TILE;
  const float* hb = hin + b * C * T;

  const int co0 = wave * 32;
  const int kq = quad * 8;
  const int off1 = (wg >> 3) & 15;   // stagger start chunk (XCD-local index)
  const int off2 = (wg >> 3) & 7;
  const u16* b1 = pw1 + wave * 32768 + lane * 8;   // contiguous DMA source, phase 1
  const u16* b2 = pw2 + wave * 8192 + lane * 8;    // phase 2
  u16* wreg0 = wb + wave * 2048;
  u16* wreg1 = wb + 16384 + wave * 2048;
  const int aoff = lane * 8;

  // ---- issue phase-1 chunks off1, off1+1 ----
#pragma unroll
  for (int cc = 0; cc < 2; ++cc) {
    u16* ld = cc ? wreg1 : wreg0;
    const u16* gs = b1 + ((off1 + cc) & 15) * 2048;
    gl_lds16(gs, ld);
    gl_lds16(gs + 512, ld + 512);
    gl_lds16(gs + 1024, ld + 1024);
    gl_lds16(gs + 1536, ld + 1536);
  }

  // ---- stage B1: smem[n][2ci+tap] ----
  const int n4 = tid & 15;
  const int cib = tid >> 4;
  float4 v[16];
  const bool al4 = ((dil & 3) == 0);
  if (t0 >= dil) {
#pragma unroll
    for (int it2 = 0; it2 < 16; ++it2) {
      int ci = (cib + it2 * 32) & 255;
      int tap = it2 >> 3;
      int tb = t0 + n4 * 4 - (tap ? 0 : dil);
      const float* p = hb + ci * T + tb;
      if (tap || al4) {
        v[it2] = *(const float4*)p;
      } else {
        v[it2].x = p[0]; v[it2].y = p[1]; v[it2].z = p[2]; v[it2].w = p[3];
      }
    }
  } else {
#pragma unroll
    for (int it2 = 0; it2 < 16; ++it2) {
      int ci = (cib + it2 * 32) & 255;
      int tap = it2 >> 3;
      int tb = t0 + n4 * 4 - (tap ? 0 : dil);
      const float* p = hb + ci * T + tb;
      if (tap) {
        v[it2] = *(const float4*)p;
      } else {
        v[it2].x = (tb + 0 >= 0) ? p[0] : 0.f;
        v[it2].y = (tb + 1 >= 0) ? p[1] : 0.f;
        v[it2].z = (tb + 2 >= 0) ? p[2] : 0.f;
        v[it2].w = (tb + 3 >= 0) ? p[3] : 0.f;
      }
    }
  }
#pragma unroll
  for (int it2 = 0; it2 < 8; ++it2) {
    int ci = (cib + it2 * 32) & 255;
    const float* p0 = (const float*)&v[it2];
    const float* p1 = (const float*)&v[it2 + 8];
#pragma unroll
    for (int r = 0; r < 4; ++r) {
      unsigned w32 = (unsigned)f2bf(p0[r]) | ((unsigned)f2bf(p1[r]) << 16);
      *(unsigned*)(&smem[swz(n4 * 4 + r, 2 * ci)]) = w32;
    }
  }
  __syncthreads();   // drains vmcnt(0): first two chunks landed

  // ---- phase 1: [f;g] = W_fg @ B1, M=512 K=512 N=64 (staggered chunk order) ----
  f32x4 acc[4][4];
#pragma unroll
  for (int m = 0; m < 4; ++m)
#pragma unroll
    for (int nt = 0; nt < 4; ++nt)
      acc[m][nt] = (f32x4){0.f, 0.f, 0.f, 0.f};

#pragma unroll
  for (int c = 0; c < 16; ++c) {
    if (c < 15) asm volatile("s_waitcnt vmcnt(4)" ::: "memory");
    else        asm volatile("s_waitcnt vmcnt(0)" ::: "memory");
    const u16* wr_ = (c & 1) ? wreg1 : wreg0;
    bf16x8 af0 = *(const bf16x8*)(wr_ + aoff);
    bf16x8 af1 = *(const bf16x8*)(wr_ + 512 + aoff);
    bf16x8 af2 = *(const bf16x8*)(wr_ + 1024 + aoff);
    bf16x8 af3 = *(const bf16x8*)(wr_ + 1536 + aoff);
    const int kk = ((c + off1) & 15) * 32 + kq;
    bf16x8 bfr[4];
#pragma unroll
    for (int nt = 0; nt < 4; ++nt)
      bfr[nt] = *(const bf16x8*)(&smem[swz(nt * 16 + ncol, kk)]);
#pragma unroll
    for (int nt = 0; nt < 4; ++nt) {
      acc[0][nt] = __builtin_amdgcn_mfma_f32_16x16x32_bf16(af0, bfr[nt], acc[0][nt], 0, 0, 0);
      acc[1][nt] = __builtin_amdgcn_mfma_f32_16x16x32_bf16(af1, bfr[nt], acc[1][nt], 0, 0, 0);
      acc[2][nt] = __builtin_amdgcn_mfma_f32_16x16x32_bf16(af2, bfr[nt], acc[2][nt], 0, 0, 0);
      acc[3][nt] = __builtin_amdgcn_mfma_f32_16x16x32_bf16(af3, bfr[nt], acc[3][nt], 0, 0, 0);
    }
    if (c + 2 < 16) {
      asm volatile("s_waitcnt lgkmcnt(0)" ::: "memory");
      u16* ld = (c & 1) ? wreg1 : wreg0;
      const u16* gs = b1 + ((c + 2 + off1) & 15) * 2048;
      gl_lds16(gs, ld);
      gl_lds16(gs + 512, ld + 512);
      gl_lds16(gs + 1024, ld + 1024);
      gl_lds16(gs + 1536, ld + 1536);
    }
  }

  // ---- issue phase-2 (res-only) chunks off2, off2+1 ----
#pragma unroll
  for (int cc = 0; cc < 2; ++cc) {
    u16* ld = cc ? wreg1 : wreg0;
    const u16* gs = b2 + ((off2 + cc) & 7) * 1024;
    gl_lds16(gs, ld);
    gl_lds16(gs + 512, ld + 512);
  }
  __syncthreads();   // B1 reads done + p2 first chunks landed

  // ---- gating -> B2[k=co][n] in LDS, plus row-sum accumulation for skip ----
  float* rsb = rowsum_l + b * C;
#pragma unroll
  for (int j = 0; j < 2; ++j) {
    const int cob = co0 + j * 16 + quad * 4;
    float bfv[4], bgv[4], rs[4];
#pragma unroll
    for (int r = 0; r < 4; ++r) {
      bfv[r] = bfb[cob + r];
      bgv[r] = bgb[cob + r];
      rs[r] = 0.f;
    }
#pragma unroll
    for (int nt = 0; nt < 4; ++nt) {
      const int n = nt * 16 + ncol;
      u16 pk[4];
#pragma unroll
      for (int r = 0; r < 4; ++r) {
        float fv = acc[j][nt][r] + bfv[r];
        float gv = acc[2 + j][nt][r] + bgv[r];
        float th = 1.f - 2.f / (__expf(2.f * fv) + 1.f);
        float sg = 1.f / (1.f + __expf(-gv));
        float o = th * sg;
        rs[r] += o;
        pk[r] = f2bf(o);
      }
      uint2 w;
      w.x = (unsigned)pk[0] | ((unsigned)pk[1] << 16);
      w.y = (unsigned)pk[2] | ((unsigned)pk[3] << 16);
      *(uint2*)(&smem[swz(n, cob)]) = w;
    }
#pragma unroll
    for (int r = 0; r < 4; ++r) {
      float s = rs[r];
      s += __shfl_xor(s, 1);
      s += __shfl_xor(s, 2);
      s += __shfl_xor(s, 4);
      s += __shfl_xor(s, 8);
      if (ncol == 0) atomicAdd(&rsb[cob + r], s);
    }
  }
  __syncthreads();

  // ---- phase 2: res = Wr @ out, M=256 K=256 N=64 (staggered) ----
  f32x4 acc2[2][4];
#pragma unroll
  for (int m = 0; m < 2; ++m)
#pragma unroll
    for (int nt = 0; nt < 4; ++nt)
      acc2[m][nt] = (f32x4){0.f, 0.f, 0.f, 0.f};

#pragma unroll
  for (int c = 0; c < 8; ++c) {
    if (c < 7) asm volatile("s_waitcnt vmcnt(2)" ::: "memory");
    else       asm volatile("s_waitcnt vmcnt(0)" ::: "memory");
    const u16* wr_ = (c & 1) ? wreg1 : wreg0;
    bf16x8 af0 = *(const bf16x8*)(wr_ + aoff);
    bf16x8 af1 = *(const bf16x8*)(wr_ + 512 + aoff);
    const int kk = ((c + off2) & 7) * 32 + kq;
    bf16x8 bfr[4];
#pragma unroll
    for (int nt = 0; nt < 4; ++nt)
      bfr[nt] = *(const bf16x8*)(&smem[swz(nt * 16 + ncol, kk)]);
#pragma unroll
    for (int nt = 0; nt < 4; ++nt) {
      acc2[0][nt] = __builtin_amdgcn_mfma_f32_16x16x32_bf16(af0, bfr[nt], acc2[0][nt], 0, 0, 0);
      acc2[1][nt] = __builtin_amdgcn_mfma_f32_16x16x32_bf16(af1, bfr[nt], acc2[1][nt], 0, 0, 0);
    }
    if (c + 2 < 8) {
      asm volatile("s_waitcnt lgkmcnt(0)" ::: "memory");
      u16* ld = (c & 1) ? wreg1 : wreg0;
      const u16* gs = b2 + ((c + 2 + off2) & 7) * 1024;
      gl_lds16(gs, ld);
      gl_lds16(gs + 512, ld + 512);
    }
  }
  __syncthreads();   // all waves done reading B2; LDS free for transpose

  // ---- epilogue: transpose res through LDS (f32, stride 66), float4 stores ----
  float* fb = (float*)smem;   // [256][66] f32
#pragma unroll
  for (int m = 0; m < 2; ++m) {
    const int cob = co0 + m * 16 + quad * 4;
#pragma unroll
    for (int nt = 0; nt < 4; ++nt) {
      const int t = nt * 16 + ncol;
#pragma unroll
      for (int r = 0; r < 4; ++r)
        fb[(cob + r) * 66 + t] = acc2[m][nt][r] + brb[cob + r];
    }
  }
  __syncthreads();
  float* ho = hout + b * C * T;
#pragma unroll
  for (int it2 = 0; it2 < 8; ++it2) {
    const int ci = cib + it2 * 32;
    const float* fr = fb + ci * 66 + n4 * 4;
    float4 o;
    o.x = fr[0] + v[it2 + 8].x;
    o.y = fr[1] + v[it2 + 8].y;
    o.z = fr[2] + v[it2 + 8].z;
    o.w = fr[3] + v[it2 + 8].w;
    *(float4*)(ho + ci * T + t0 + n4 * 4) = o;
  }
}

// per-layer skip matvec: pooled[b][co] += Ws_l[co,:] . rowsum[l][b,:] + T*bs_l[co]
__global__ __launch_bounds__(256) void k_skip(
    const float* __restrict__ encWs, const float* __restrict__ encbs,
    const float* __restrict__ rowsum, float* __restrict__ pooled) {
  __shared__ float rs[B][C];
  const int l = blockIdx.x;
  const int co = threadIdx.x;
  for (int i = co; i < B * C; i += 256) rs[i >> 8][i & 255] = rowsum[l * B * C + i];
  __syncthreads();
  const float* Wrow = encWs + (size_t)l * C * C + co * C;
  float bs = encbs[l * C + co] * (float)T;
  float d[B] = {0.f, 0.f, 0.f, 0.f};
  for (int ci = 0; ci < C; ci += 4) {
    float4 w = *(const float4*)(Wrow + ci);
#pragma unroll
    for (int b = 0; b < B; ++b)
      d[b] += w.x * rs[b][ci] + w.y * rs[b][ci + 1] + w.z * rs[b][ci + 2] + w.w * rs[b][ci + 3];
  }
#pragma unroll
  for (int b = 0; b < B; ++b) atomicAdd(&pooled[b * C + co], d[b] + bs);
}

// wave-per-dot FC
__global__ __launch_bounds__(256) void k_fc(
    const float* __restrict__ pooled,
    const float* __restrict__ muW, const float* __restrict__ mub,
    const float* __restrict__ lvW, const float* __restrict__ lvb,
    float* __restrict__ mlbuf, float* __restrict__ dout) {
  __shared__ float pm[B * C];
  const int tid = threadIdx.x;
  for (int i = tid; i < B * C; i += 256) pm[i] = pooled[i] * (1.f / (float)T);
  __syncthreads();
  const int waveG = blockIdx.x * 4 + (tid >> 6);
  const int lane = tid & 63;
  for (int j = 0; j < 16; ++j) {
    int d = waveG * 16 + j;
    int b = d >> 8, r = d & 255, which = r >> 7, l = r & 127;
    const float* Wrow = (which ? lvW : muW) + l * C;
    const float* p = pm + b * C;
    float s = Wrow[lane] * p[lane] + Wrow[lane + 64] * p[lane + 64] +
              Wrow[lane + 128] * p[lane + 128] + Wrow[lane + 192] * p[lane + 192];
#pragma unroll
    for (int off = 32; off; off >>= 1) s += __shfl_xor(s, off);
    if (lane == 0) {
      float val = s + (which ? lvb[l] : mub[l]);
      mlbuf[which * 512 + b * 128 + l] = val;
      dout[4 + which * 512 + b * 128 + l] = val;
    }
  }
}

// Decoder: 1 block, 16 waves, contiguous-packed LDS-streamed weights.
__global__ __launch_bounds__(1024, 1) void k_dec(
    const float* __restrict__ mlbuf, const float* __restrict__ eps,
    const u16* __restrict__ tdin, const float* __restrict__ dinb,
    const u16* __restrict__ pdfg, const float* __restrict__ dbf,
    const float* __restrict__ dbg,
    const u16* __restrict__ pdr, const float* __restrict__ dbr,
    const float* __restrict__ outW, const float* __restrict__ outb,
    float* __restrict__ dout) {
  extern __shared__ __align__(16) u16 dsm[];   // 16 waves x 4 bufs x 1024 elems = 128KB
  __shared__ __align__(16) u16 Ah[16][264];
  __shared__ __align__(16) u16 Ao[16][264];
  __shared__ float h2f[4][256];
  __shared__ float outred[4];
  const int tid = threadIdx.x;
  const int wave = tid >> 6;
  const int lane = tid & 63;
  const int ncol = lane & 15;
  const int quad = lane >> 4;
  const int kq = quad * 8;
  const int co = wave * 16 + ncol;
  u16* wreg = dsm + wave * 4096;

  bf16x8 tdw[4];
  {
    const u16* wp = tdin + co * 128;
#pragma unroll
    for (int it = 0; it < 4; ++it) tdw[it] = *(const bf16x8*)(wp + it * 32 + kq);
  }

  if (tid < 512) {
    int b = tid >> 7, l = tid & 127;
    float mu = mlbuf[b * 128 + l];
    float lv = mlbuf[512 + b * 128 + l];
    Ah[b][l] = f2bf(mu + eps[b * 128 + l] * expf(0.5f * lv));
  }
  if (tid < 4) outred[tid] = 0.f;
  __syncthreads();

  // dec_in
  {
    f32x4 acch = (f32x4){0.f, 0.f, 0.f, 0.f};
#pragma unroll
    for (int it = 0; it < 4; ++it) {
      bf16x8 af = *(const bf16x8*)(&Ah[ncol][it * 32 + kq]);
      acch = __builtin_amdgcn_mfma_f32_16x16x32_bf16(af, tdw[it], acch, 0, 0, 0);
    }
    __syncthreads();
    if (quad == 0) {
      float bias = dinb[co];
#pragma unroll
      for (int r = 0; r < 4; ++r) {
        float hv = acch[r] + bias;
        h2f[r][co] = hv;
        Ah[r][co] = f2bf(hv);
      }
    }
  }
  // prefetch layer-0 f/g chunks 0..3
  {
    const u16* fb = pdfg + wave * 8192 + lane * 8;
#pragma unroll
    for (int cc = 0; cc < 4; ++cc) {
      gl_lds16(fb + cc * 1024, wreg + cc * 1024);
      gl_lds16(fb + cc * 1024 + 512, wreg + cc * 1024 + 512);
    }
  }
  __syncthreads();

  for (int i = 0; i < NDEC; ++i) {
    const u16* fb = pdfg + (i * 16 + wave) * 8192 + lane * 8;
    const u16* rb = pdr + (i * 16 + wave) * 4096 + lane * 8;

    f32x4 accf = (f32x4){0.f, 0.f, 0.f, 0.f};
    f32x4 accg = (f32x4){0.f, 0.f, 0.f, 0.f};
#pragma unroll
    for (int c = 0; c < 8; ++c) {
      if (c == 4) asm volatile("s_waitcnt vmcnt(6)" ::: "memory");
      else if (c == 5) asm volatile("s_waitcnt vmcnt(4)" ::: "memory");
      else if (c == 6) asm volatile("s_waitcnt vmcnt(2)" ::: "memory");
      else if (c == 7) asm volatile("s_waitcnt vmcnt(0)" ::: "memory");
      const u16* bufp = wreg + (c & 3) * 1024;
      bf16x8 bf_ = *(const bf16x8*)(bufp + lane * 8);
      bf16x8 bg_ = *(const bf16x8*)(bufp + 512 + lane * 8);
      bf16x8 af = *(const bf16x8*)(&Ah[ncol][c * 32 + kq]);
      accf = __builtin_amdgcn_mfma_f32_16x16x32_bf16(af, bf_, accf, 0, 0, 0);
      accg = __builtin_amdgcn_mfma_f32_16x16x32_bf16(af, bg_, accg, 0, 0, 0);
      if (c < 4) {
        asm volatile("s_waitcnt lgkmcnt(0)" ::: "memory");
        gl_lds16(fb + (c + 4) * 1024, wreg + (c & 3) * 1024);
        gl_lds16(fb + (c + 4) * 1024 + 512, wreg + (c & 3) * 1024 + 512);
      }
    }
    asm volatile("s_waitcnt lgkmcnt(0)" ::: "memory");
#pragma unroll
    for (int cc = 0; cc < 4; ++cc) gl_lds16(rb + cc * 512, wreg + cc * 1024);

    if (quad == 0) {
      float bfv = dbf[i * C + co];
      float bgv = dbg[i * C + co];
#pragma unroll
      for (int r = 0; r < 4; ++r) {
        float fv = accf[r] + bfv;
        float gv = accg[r] + bgv;
        float th = 1.f - 2.f / (__expf(2.f * fv) + 1.f);
        float sg = 1.f / (1.f + __expf(-gv));
        Ao[r][co] = f2bf(th * sg);
      }
    }
    __syncthreads();

    f32x4 accr = (f32x4){0.f, 0.f, 0.f, 0.f};
#pragma unroll
    for (int c = 0; c < 8; ++c) {
      if (c == 4) asm volatile("s_waitcnt vmcnt(3)" ::: "memory");
      else if (c == 5) asm volatile("s_waitcnt vmcnt(2)" ::: "memory");
      else if (c == 6) asm volatile("s_waitcnt vmcnt(1)" ::: "memory");
      else if (c == 7) asm volatile("s_waitcnt vmcnt(0)" ::: "memory");
      bf16x8 br_ = *(const bf16x8*)(wreg + (c & 3) * 1024 + lane * 8);
      bf16x8 af = *(const bf16x8*)(&Ao[ncol][c * 32 + kq]);
      accr = __builtin_amdgcn_mfma_f32_16x16x32_bf16(af, br_, accr, 0, 0, 0);
      if (c < 4) {
        asm volatile("s_waitcnt lgkmcnt(0)" ::: "memory");
        gl_lds16(rb + (c + 4) * 512, wreg + (c & 3) * 1024);
      }
    }
    if (i + 1 < NDEC) {
      const u16* nfb = pdfg + ((i + 1) * 16 + wave) * 8192 + lane * 8;
      asm volatile("s_waitcnt lgkmcnt(0)" ::: "memory");
#pragma unroll
      for (int cc = 0; cc < 4; ++cc) {
        gl_lds16(nfb + cc * 1024, wreg + cc * 1024);
        gl_lds16(nfb + cc * 1024 + 512, wreg + cc * 1024 + 512);
      }
    }
    if (quad == 0) {
      float brv = dbr[i * C + co];
#pragma unroll
      for (int r = 0; r < 4; ++r) {
        float hv = h2f[r][co] + accr[r] + brv;
        h2f[r][co] = hv;
        Ah[r][co] = f2bf(hv);
      }
    }
    __syncthreads();
  }

  {
    int b = tid >> 8, c = tid & 255;
    float val = outW[c] * h2f[b][c];
#pragma unroll
    for (int off = 32; off; off >>= 1) val += __shfl_xor(val, off);
    if (lane == 0) atomicAdd(&outred[b], val);
  }
  __syncthreads();
  if (tid < 4) dout[tid] = outred[tid] + outb[0];
}

extern "C" void kernel_launch(void* const* d_in, const int* in_sizes, int n_in,
                              void* d_out, int out_size, void* d_ws, size_t ws_size,
                              hipStream_t stream) {
  const float* x      = (const float*)d_in[0];
  const float* eps    = (const float*)d_in[1];
  const float* encinW = (const float*)d_in[2];
  const float* encinb = (const float*)d_in[3];
  const float* encWf  = (const float*)d_in[4];
  const float* encbf  = (const float*)d_in[5];
  const float* encWg  = (const float*)d_in[6];
  const float* encbg  = (const float*)d_in[7];
  const float* encWr  = (const float*)d_in[8];
  const float* encbr  = (const float*)d_in[9];
  const float* encWs  = (const float*)d_in[10];
  const float* encbs  = (const float*)d_in[11];
  const float* muW    = (const float*)d_in[12];
  const float* mub    = (const float*)d_in[13];
  const float* lvW    = (const float*)d_in[14];
  const float* lvb    = (const float*)d_in[15];
  const float* dinW   = (const float*)d_in[16];
  const float* dinb   = (const float*)d_in[17];
  const float* dWf    = (const float*)d_in[18];
  const float* dbf    = (const float*)d_in[19];
  const float* dWg    = (const float*)d_in[20];
  const float* dbg    = (const float*)d_in[21];
  const float* dWr    = (const float*)d_in[22];
  const float* dbr    = (const float*)d_in[23];
  const float* outW   = (const float*)d_in[24];
  const float* outb   = (const float*)d_in[25];
  float* dout = (float*)d_out;

  char* ws = (char*)d_ws;
  float* hA = (float*)ws;
  float* hB = hA + (size_t)B * C * T;
  float* pooled = hB + (size_t)B * C * T;
  float* mlbuf = pooled + B * C;
  float* rowsum = mlbuf + 1024;                     // [40][4][256] f32
  u16* penc1 = (u16*)(rowsum + NENC * B * C);       // 10,485,760
  u16* penc2 = penc1 + (size_t)10485760;            // 2,621,440
  u16* pdfg = penc2 + (size_t)2621440;              // 1,310,720
  u16* pdr = pdfg + (size_t)1310720;                // 655,360
  u16* tdin = pdr + (size_t)655360;                 // 32,768

  (void)hipFuncSetAttribute(reinterpret_cast<const void*>(k_enc),
                            hipFuncAttributeMaxDynamicSharedMemorySize, 131072);
  (void)hipFuncSetAttribute(reinterpret_cast<const void*>(k_dec),
                            hipFuncAttributeMaxDynamicSharedMemorySize, 131072);

  k_pack1<<<(1310720 + 255) / 256, 256, 0, stream>>>(encWf, encWg, penc1, 1310720);
  k_pack2<<<(327680 + 255) / 256, 256, 0, stream>>>(encWr, penc2, 327680);
  k_packd<<<(249856 + 255) / 256, 256, 0, stream>>>(dWf, dWg, dWr, dinW, pdfg, pdr, tdin);

  const int nZ = B * C + 1024 + NENC * B * C;
  k_zero<<<(nZ + 255) / 256, 256, 0, stream>>>(pooled, nZ);
  k_input<<<(B * C * T) / 256, 256, 0, stream>>>(x, encinW, encinb, hA);

  for (int i = 0; i < NENC; ++i) {
    const int dil = 1 << (i % 10);
    const float* hi = (i & 1) ? hB : hA;
    float* ho = (i & 1) ? hA : hB;
    k_enc<<<256, 512, 131072, stream>>>(
        hi, ho, rowsum + (size_t)i * B * C,
        penc1 + (size_t)i * 262144, encbf + (size_t)i * C,
        encbg + (size_t)i * C,
        penc2 + (size_t)i * 65536, encbr + (size_t)i * C,
        dil);
  }

  k_skip<<<NENC, 256, 0, stream>>>(encWs, encbs, rowsum, pooled);
  k_fc<<<16, 256, 0, stream>>>(pooled, muW, mub, lvW, lvb, mlbuf, dout);
  k_dec<<<1, 1024, 131072, stream>>>(mlbuf, eps, tdin, dinb, pdfg, dbf, dbg,
                                     pdr, dbr, outW, outb, dout);
}